// Round 1
// baseline (328.192 us; speedup 1.0000x reference)
//
#include <hip/hip_runtime.h>
#include <math.h>

// Dims: x[64,512,28,28] -> out[64,544,28,28] fp32
static constexpr int BB    = 64;
static constexpr int C_IN  = 512;
static constexpr int C_MID = 128;
static constexpr int C_OUT = 32;
static constexpr int C_TOT = 544;
static constexpr int HW    = 784;   // 28*28

// ---- workspace layout (float offsets). Total ~26.25 MB ----
static constexpr size_t H2_OFF    = 0;                         // 64*128*784 = 6,422,528
static constexpr size_t QW1_OFF   = 6422528;                   // 128*512
static constexpr size_t QW2_OFF   = QW1_OFF + 65536;           // [ci][co][12] = 128*32*12
static constexpr size_t PSTAT_OFF = QW2_OFF + 49152;           // [512][8][4]
static constexpr size_t BNA_OFF   = PSTAT_OFF + 16384;         // 512
static constexpr size_t BNB_OFF   = BNA_OFF + 512;             // 512
static constexpr size_t CMAX_OFF  = BNB_OFF + 512;             // 128*16
static constexpr size_t CMIN_OFF  = CMAX_OFF + 2048;
static constexpr size_t CSUM_OFF  = CMIN_OFF + 2048;
static constexpr size_t A2_OFF    = CSUM_OFF + 2048;           // 128
static constexpr size_t B2_OFF    = A2_OFF + 128;
static constexpr size_t QRW_OFF   = B2_OFF + 128;
static constexpr size_t QRB_OFF   = QRW_OFF + 128;
static constexpr size_t SCAL_OFF  = QRB_OFF + 128;             // 16 scalars
// SCAL: 0=mn1 1=scale1 2=inv1 3=mn3 4=scale3 5=inv3 6=mx1 7=mx3

#define DEVFN __device__ __forceinline__

DEVFN float qact(float v, float mn, float mx, float inv, float sc) {
    // quantize-dequantize with clip (mn/mx are true range -> matches jnp.clip)
    v = fminf(fmaxf(v, mn), mx);
    return fmaf(rintf((v - mn) * inv), sc, mn);   // rintf == round-half-even == jnp.round
}

DEVFN int swz(int col, int row) {  // XOR swizzle of 4-float groups, preserves b128 alignment
    return (((col >> 2) ^ (row & 7)) << 2) | (col & 3);
}

// ---------- K0: per-channel x stats (8 image-groups) + concat copy out[:, :512] = x ----------
__global__ __launch_bounds__(256) void k_stats_copy(const float* __restrict__ x,
                                                    float* __restrict__ out,
                                                    float* __restrict__ ws) {
    const int c = blockIdx.x, bg = blockIdx.y, tid = threadIdx.x;
    float s = 0.f, s2 = 0.f, mn = INFINITY, mx = -INFINITY;
    for (int i = tid; i < 8 * 196; i += 256) {     // 8 images * 196 float4 per (b,c) row
        const int b = bg * 8 + i / 196, j = i % 196;
        const float4 v = ((const float4*)(x + ((size_t)b * C_IN + c) * HW))[j];
        ((float4*)(out + ((size_t)b * C_TOT + c) * HW))[j] = v;
        s  += (v.x + v.y) + (v.z + v.w);
        s2 += v.x * v.x + v.y * v.y + v.z * v.z + v.w * v.w;
        mn = fminf(mn, fminf(fminf(v.x, v.y), fminf(v.z, v.w)));
        mx = fmaxf(mx, fmaxf(fmaxf(v.x, v.y), fmaxf(v.z, v.w)));
    }
    __shared__ float r0[256], r1[256], r2[256], r3[256];
    r0[tid] = s; r1[tid] = s2; r2[tid] = mn; r3[tid] = mx;
    __syncthreads();
    for (int off = 128; off > 0; off >>= 1) {
        if (tid < off) {
            r0[tid] += r0[tid + off];
            r1[tid] += r1[tid + off];
            r2[tid] = fminf(r2[tid], r2[tid + off]);
            r3[tid] = fmaxf(r3[tid], r3[tid + off]);
        }
        __syncthreads();
    }
    if (tid == 0) {
        float* p = ws + PSTAT_OFF + ((size_t)c * 8 + bg) * 4;
        p[0] = r0[0]; p[1] = r1[0]; p[2] = r2[0]; p[3] = r3[0];
    }
}

// ---------- K1: BN coefs + h1 range + quantize all weights ----------
__global__ __launch_bounds__(256) void k_prep1(const float* __restrict__ bn1_w,
                                               const float* __restrict__ bn1_b,
                                               const float* __restrict__ conv1_w,
                                               const float* __restrict__ rbn_w,
                                               const float* __restrict__ rbn_b,
                                               const float* __restrict__ conv2_w,
                                               float* __restrict__ ws) {
    const int tid = threadIdx.x;
    __shared__ float ra[256], rb[256];
    __shared__ float s_mn, s_sc;

    // --- Phase A: per-channel BN affine + global h1=relu(bn(x)) range via channel endpoints
    float lmn = INFINITY, lmx = -INFINITY;
    for (int c = tid; c < 512; c += 256) {
        const float* p = ws + PSTAT_OFF + (size_t)c * 32;
        float s = 0.f, s2 = 0.f, mn = INFINITY, mx = -INFINITY;
        for (int g = 0; g < 8; ++g) {
            s += p[g * 4 + 0]; s2 += p[g * 4 + 1];
            mn = fminf(mn, p[g * 4 + 2]); mx = fmaxf(mx, p[g * 4 + 3]);
        }
        const float n = 50176.f;
        const float mean = s / n;
        const float var  = s2 / n - mean * mean;     // biased variance
        const float rstd = rsqrtf(var + 1e-5f);
        const float A  = rstd * bn1_w[c];
        const float Bc = bn1_b[c] - mean * A;
        ws[BNA_OFF + c] = A; ws[BNB_OFF + c] = Bc;
        const float v1 = A * mn + Bc, v2 = A * mx + Bc;   // affine endpoints (sign-safe)
        lmn = fminf(lmn, fmaxf(0.f, fminf(v1, v2)));
        lmx = fmaxf(lmx, fmaxf(0.f, fmaxf(v1, v2)));
    }
    ra[tid] = lmn; rb[tid] = lmx;
    __syncthreads();
    for (int off = 128; off > 0; off >>= 1) {
        if (tid < off) { ra[tid] = fminf(ra[tid], ra[tid + off]); rb[tid] = fmaxf(rb[tid], rb[tid + off]); }
        __syncthreads();
    }
    if (tid == 0) {
        const float mn1 = ra[0], mx1 = rb[0];
        const float sc = fmaxf((mx1 - mn1) / 255.f, 1e-8f);
        ws[SCAL_OFF + 0] = mn1; ws[SCAL_OFF + 1] = sc; ws[SCAL_OFF + 2] = 1.f / sc; ws[SCAL_OFF + 6] = mx1;
    }
    __syncthreads();

    // --- Phase B: quantize conv1_w (65536 floats)
    {
        float mn = INFINITY, mx = -INFINITY;
        for (int i = tid; i < 16384; i += 256) {
            const float4 v = ((const float4*)conv1_w)[i];
            mn = fminf(mn, fminf(fminf(v.x, v.y), fminf(v.z, v.w)));
            mx = fmaxf(mx, fmaxf(fmaxf(v.x, v.y), fmaxf(v.z, v.w)));
        }
        ra[tid] = mn; rb[tid] = mx;
        __syncthreads();
        for (int off = 128; off > 0; off >>= 1) {
            if (tid < off) { ra[tid] = fminf(ra[tid], ra[tid + off]); rb[tid] = fmaxf(rb[tid], rb[tid + off]); }
            __syncthreads();
        }
        if (tid == 0) { s_mn = ra[0]; s_sc = fmaxf((rb[0] - ra[0]) / 255.f, 1e-8f); }
        __syncthreads();
        const float mnw = s_mn, scw = s_sc;
        for (int i = tid; i < 16384; i += 256) {
            float4 v = ((const float4*)conv1_w)[i];
            v.x = fmaf(rintf((v.x - mnw) / scw), scw, mnw);
            v.y = fmaf(rintf((v.y - mnw) / scw), scw, mnw);
            v.z = fmaf(rintf((v.z - mnw) / scw), scw, mnw);
            v.w = fmaf(rintf((v.w - mnw) / scw), scw, mnw);
            ((float4*)(ws + QW1_OFF))[i] = v;
        }
        __syncthreads();
    }

    // --- Phase C: quantize conv2_w into padded [ci][co][12] layout
    {
        float mn = INFINITY, mx = -INFINITY;
        for (int i = tid; i < 9216; i += 256) {   // 36864/4
            const float4 v = ((const float4*)conv2_w)[i];
            mn = fminf(mn, fminf(fminf(v.x, v.y), fminf(v.z, v.w)));
            mx = fmaxf(mx, fmaxf(fmaxf(v.x, v.y), fmaxf(v.z, v.w)));
        }
        ra[tid] = mn; rb[tid] = mx;
        __syncthreads();
        for (int off = 128; off > 0; off >>= 1) {
            if (tid < off) { ra[tid] = fminf(ra[tid], ra[tid + off]); rb[tid] = fmaxf(rb[tid], rb[tid + off]); }
            __syncthreads();
        }
        if (tid == 0) { s_mn = ra[0]; s_sc = fmaxf((rb[0] - ra[0]) / 255.f, 1e-8f); }
        __syncthreads();
        const float mnw = s_mn, scw = s_sc;
        for (int i = tid; i < 36864; i += 256) {
            const int co = i / 1152, r = i % 1152, ci = r / 9, t = r % 9;
            const float v = conv2_w[i];
            ws[QW2_OFF + ((size_t)ci * 32 + co) * 12 + t] = fmaf(rintf((v - mnw) / scw), scw, mnw);
        }
        for (int i = tid; i < 4096; i += 256) {   // zero pads
            float* pz = ws + QW2_OFF + (size_t)i * 12;
            pz[9] = 0.f; pz[10] = 0.f; pz[11] = 0.f;
        }
        __syncthreads();
    }

    // --- Phase D: quantize rbn_w, rbn_b (128 each)
    for (int which = 0; which < 2; ++which) {
        const float* src = which ? rbn_b : rbn_w;
        const size_t dst = which ? QRB_OFF : QRW_OFF;
        float v = 0.f, mn = INFINITY, mx = -INFINITY;
        if (tid < 128) { v = src[tid]; mn = v; mx = v; }
        ra[tid] = mn; rb[tid] = mx;
        __syncthreads();
        for (int off = 128; off > 0; off >>= 1) {
            if (tid < off) { ra[tid] = fminf(ra[tid], ra[tid + off]); rb[tid] = fmaxf(rb[tid], rb[tid + off]); }
            __syncthreads();
        }
        if (tid == 0) { s_mn = ra[0]; s_sc = fmaxf((rb[0] - ra[0]) / 255.f, 1e-8f); }
        __syncthreads();
        if (tid < 128) ws[dst + tid] = fmaf(rintf((v - s_mn) / s_sc), s_sc, s_mn);
        __syncthreads();
    }
}

// ---------- K2: 1x1 conv (GEMM 128x512 @ 512x784 per batch), BN+ReLU+quant fused on load ----------
__global__ __launch_bounds__(256, 2) void k_conv1(const float* __restrict__ x, float* __restrict__ ws) {
    __shared__ __align__(16) float ht[32][128];   // [k][p] quantized h1
    __shared__ __align__(16) float wt[32][128];   // [k][co] quantized w
    const int tid = threadIdx.x;
    const int pt = blockIdx.x, b = blockIdx.y;    // p-tile 0..6, batch
    const int p0 = pt * 128;
    const float mn1 = ws[SCAL_OFF + 0], sc1 = ws[SCAL_OFF + 1];
    const float inv1 = ws[SCAL_OFF + 2], mx1 = ws[SCAL_OFF + 6];
    const int cog = tid >> 4, pg = tid & 15;      // 16 x 16 thread grid -> 8co x 8p each
    float acc[8][8];
#pragma unroll
    for (int i = 0; i < 8; ++i)
#pragma unroll
        for (int j = 0; j < 8; ++j) acc[i][j] = 0.f;

    for (int kc = 0; kc < 16; ++kc) {
        const int ci0 = kc * 32;
#pragma unroll
        for (int i = 0; i < 4; ++i) {             // stage h1-tile: 32ci x 128p
            const int lin = tid + i * 256;
            const int k = lin >> 5, j = lin & 31;
            const int p = p0 + j * 4;
            float4 v = make_float4(0.f, 0.f, 0.f, 0.f);
            if (p < HW) v = *((const float4*)(x + ((size_t)b * C_IN + ci0 + k) * HW + p));
            const float A = ws[BNA_OFF + ci0 + k], Bc = ws[BNB_OFF + ci0 + k];
            v.x = qact(fmaxf(0.f, fmaf(v.x, A, Bc)), mn1, mx1, inv1, sc1);
            v.y = qact(fmaxf(0.f, fmaf(v.y, A, Bc)), mn1, mx1, inv1, sc1);
            v.z = qact(fmaxf(0.f, fmaf(v.z, A, Bc)), mn1, mx1, inv1, sc1);
            v.w = qact(fmaxf(0.f, fmaf(v.w, A, Bc)), mn1, mx1, inv1, sc1);
            *((float4*)&ht[k][j * 4]) = v;
        }
#pragma unroll
        for (int i = 0; i < 4; ++i) {             // stage w-tile transposed: [k][co]
            const int lin = tid + i * 256;
            const int co = lin >> 3, jj = lin & 7;
            const float4 w = *((const float4*)(ws + QW1_OFF + (size_t)co * 512 + ci0 + jj * 4));
            wt[jj * 4 + 0][co] = w.x; wt[jj * 4 + 1][co] = w.y;
            wt[jj * 4 + 2][co] = w.z; wt[jj * 4 + 3][co] = w.w;
        }
        __syncthreads();
#pragma unroll 4
        for (int k = 0; k < 32; ++k) {
            const float4 a0 = *((const float4*)&wt[k][cog * 8]);
            const float4 a1 = *((const float4*)&wt[k][cog * 8 + 4]);
            const float4 b0 = *((const float4*)&ht[k][pg * 8]);
            const float4 b1 = *((const float4*)&ht[k][pg * 8 + 4]);
            const float av[8] = {a0.x, a0.y, a0.z, a0.w, a1.x, a1.y, a1.z, a1.w};
            const float bv[8] = {b0.x, b0.y, b0.z, b0.w, b1.x, b1.y, b1.z, b1.w};
#pragma unroll
            for (int i = 0; i < 8; ++i)
#pragma unroll
                for (int j = 0; j < 8; ++j) acc[i][j] = fmaf(av[i], bv[j], acc[i][j]);
        }
        __syncthreads();
    }
    const int p = p0 + pg * 8;
    if (p < HW) {                                  // p multiple of 8 -> p<=776, both f4 stores fit
#pragma unroll
        for (int i = 0; i < 8; ++i) {
            const int co = cog * 8 + i;
            float* dst = ws + H2_OFF + ((size_t)b * C_MID + co) * HW + p;
            *((float4*)dst)       = make_float4(acc[i][0], acc[i][1], acc[i][2], acc[i][3]);
            *((float4*)(dst + 4)) = make_float4(acc[i][4], acc[i][5], acc[i][6], acc[i][7]);
        }
    }
}

// ---------- K3: RangeBN chunked stats: chunk = 4 consecutive images ----------
__global__ __launch_bounds__(256) void k_rbn_stats(float* __restrict__ ws) {
    const int c = blockIdx.x, ch = blockIdx.y, tid = threadIdx.x;
    float s = 0.f, mn = INFINITY, mx = -INFINITY;
    for (int i = tid; i < 784; i += 256) {         // 4 images * 196 float4
        const int b = ch * 4 + i / 196, j = i % 196;
        const float4 v = ((const float4*)(ws + H2_OFF + ((size_t)b * C_MID + c) * HW))[j];
        s += (v.x + v.y) + (v.z + v.w);
        mn = fminf(mn, fminf(fminf(v.x, v.y), fminf(v.z, v.w)));
        mx = fmaxf(mx, fmaxf(fmaxf(v.x, v.y), fmaxf(v.z, v.w)));
    }
    __shared__ float r0[256], r1[256], r2[256];
    r0[tid] = s; r1[tid] = mn; r2[tid] = mx;
    __syncthreads();
    for (int off = 128; off > 0; off >>= 1) {
        if (tid < off) {
            r0[tid] += r0[tid + off];
            r1[tid] = fminf(r1[tid], r1[tid + off]);
            r2[tid] = fmaxf(r2[tid], r2[tid + off]);
        }
        __syncthreads();
    }
    if (tid == 0) {
        ws[CSUM_OFF + (size_t)c * 16 + ch] = r0[0];
        ws[CMIN_OFF + (size_t)c * 16 + ch] = r1[0];
        ws[CMAX_OFF + (size_t)c * 16 + ch] = r2[0];
    }
}

// ---------- K4: RangeBN affine + h3 range ----------
__global__ __launch_bounds__(256) void k_prep2(float* __restrict__ ws) {
    const int tid = threadIdx.x;
    __shared__ float ra[256], rb[256];
    float lo = INFINITY, hi = -INFINITY;
    if (tid < 128) {
        const int c = tid;
        float mm = 0.f, mnm = 0.f, s = 0.f, cmx = -INFINITY, cmn = INFINITY;
        for (int ch = 0; ch < 16; ++ch) {
            const float a = ws[CMAX_OFF + (size_t)c * 16 + ch];
            const float m = ws[CMIN_OFF + (size_t)c * 16 + ch];
            mm += a; mnm += m; s += ws[CSUM_OFF + (size_t)c * 16 + ch];
            cmx = fmaxf(cmx, a); cmn = fminf(cmn, m);
        }
        mm *= (1.f / 16.f); mnm *= (1.f / 16.f);
        const float mean = s / 50176.f;
        const double PI_D = 3.14159265358979323846;
        const double sfd = 0.175 * (1.0 + sqrt(PI_D * log(4.0))) / sqrt(2.0 * log(3136.0));
        const float scale = 1.f / ((mm - mnm) * (float)sfd + 1e-5f);
        const float A  = scale * ws[QRW_OFF + c];
        const float Bc = ws[QRB_OFF + c] - mean * A;
        ws[A2_OFF + c] = A; ws[B2_OFF + c] = Bc;
        const float v1 = A * cmn + Bc, v2 = A * cmx + Bc;
        lo = fmaxf(0.f, fminf(v1, v2));
        hi = fmaxf(0.f, fmaxf(v1, v2));
    }
    ra[tid] = lo; rb[tid] = hi;
    __syncthreads();
    for (int off = 128; off > 0; off >>= 1) {
        if (tid < off) { ra[tid] = fminf(ra[tid], ra[tid + off]); rb[tid] = fmaxf(rb[tid], rb[tid + off]); }
        __syncthreads();
    }
    if (tid == 0) {
        const float mn3 = ra[0], mx3 = rb[0];
        const float sc = fmaxf((mx3 - mn3) / 255.f, 1e-8f);
        ws[SCAL_OFF + 3] = mn3; ws[SCAL_OFF + 4] = sc; ws[SCAL_OFF + 5] = 1.f / sc; ws[SCAL_OFF + 7] = mx3;
    }
}

// ---------- K5: 3x3 conv, RBN+ReLU+quant fused in staging, writes out[:, 512:544] ----------
__global__ __launch_bounds__(256, 2) void k_conv2(float* __restrict__ out, const float* __restrict__ ws) {
    __shared__ __align__(16) float win[8 * 32 * 12];   // [ci][co][12]
    __shared__ __align__(16) float inb[8 * 12 * 32];   // [ci][row][32], XOR-swizzled cols
    const int tid = threadIdx.x;
    const int qg = blockIdx.x, b = blockIdx.y;         // quad-group 0..6, batch
    const int co = tid & 31, q = tid >> 5;
    int gq = qg * 8 + q;
    const bool valid = gq < 49;
    if (!valid) gq = 48;
    const int qy = gq / 7, qx = gq % 7;
    const int y0 = qy * 4, x0 = qx * 4;
    const int ylo = ((qg * 8) / 7) * 4;                // padded-row window start
    const int r0 = y0 - ylo;                           // 0 or 4
    const float mn3 = ws[SCAL_OFF + 3], sc3 = ws[SCAL_OFF + 4];
    const float inv3 = ws[SCAL_OFF + 5], mx3 = ws[SCAL_OFF + 7];
    float acc[4][4];
#pragma unroll
    for (int i = 0; i < 4; ++i)
#pragma unroll
        for (int j = 0; j < 4; ++j) acc[i][j] = 0.f;

    for (int cc = 0; cc < 16; ++cc) {
        const int ci0 = cc * 8;
        __syncthreads();
        for (int i = tid; i < 768; i += 256)           // stage weights (already [ci][co][12])
            ((float4*)win)[i] = ((const float4*)(ws + QW2_OFF + (size_t)ci0 * 384))[i];
        if (tid < 96) {                                // stage 8ci x 12 padded rows x 32
            const int ci = tid / 12, rr = tid % 12;
            const int r = ylo + rr;                    // padded row id (0..29)
            float* dst = inb + (ci * 12 + rr) * 32;
            if (r <= 29) {
                if (r == 0 || r == 29) {
#pragma unroll
                    for (int cj = 0; cj < 32; ++cj) dst[swz(cj, rr)] = 0.f;
                } else {
                    const float A = ws[A2_OFF + ci0 + ci], Bc = ws[B2_OFF + ci0 + ci];
                    const float* src = ws + H2_OFF + ((size_t)b * C_MID + ci0 + ci) * HW + (r - 1) * 28;
                    dst[swz(0, rr)]  = 0.f;
                    dst[swz(29, rr)] = 0.f; dst[swz(30, rr)] = 0.f; dst[swz(31, rr)] = 0.f;
#pragma unroll
                    for (int j = 0; j < 7; ++j) {
                        const float4 v = ((const float4*)src)[j];
                        dst[swz(1 + j * 4 + 0, rr)] = qact(fmaxf(0.f, fmaf(v.x, A, Bc)), mn3, mx3, inv3, sc3);
                        dst[swz(1 + j * 4 + 1, rr)] = qact(fmaxf(0.f, fmaf(v.y, A, Bc)), mn3, mx3, inv3, sc3);
                        dst[swz(1 + j * 4 + 2, rr)] = qact(fmaxf(0.f, fmaf(v.z, A, Bc)), mn3, mx3, inv3, sc3);
                        dst[swz(1 + j * 4 + 3, rr)] = qact(fmaxf(0.f, fmaf(v.w, A, Bc)), mn3, mx3, inv3, sc3);
                    }
                }
            }
        }
        __syncthreads();
#pragma unroll
        for (int ci = 0; ci < 8; ++ci) {
            const float* wp = win + ((size_t)ci * 32 + co) * 12;
            const float4 w0 = *((const float4*)wp);
            const float4 w1 = *((const float4*)(wp + 4));
            const float  w8 = wp[8];
            const float w9[9] = {w0.x, w0.y, w0.z, w0.w, w1.x, w1.y, w1.z, w1.w, w8};
            float f[6][8];
#pragma unroll
            for (int rr2 = 0; rr2 < 6; ++rr2) {
                const int rl = r0 + rr2;
                const float* rowp = inb + (ci * 12 + rl) * 32;
                const float4 va = *((const float4*)(rowp + ((qx ^ (rl & 7)) << 2)));
                const float4 vb = *((const float4*)(rowp + (((qx + 1) ^ (rl & 7)) << 2)));
                f[rr2][0] = va.x; f[rr2][1] = va.y; f[rr2][2] = va.z; f[rr2][3] = va.w;
                f[rr2][4] = vb.x; f[rr2][5] = vb.y; f[rr2][6] = vb.z; f[rr2][7] = vb.w;
            }
#pragma unroll
            for (int ty = 0; ty < 4; ++ty)
#pragma unroll
                for (int dy = 0; dy < 3; ++dy)
#pragma unroll
                    for (int dx = 0; dx < 3; ++dx) {
                        const float wv = w9[dy * 3 + dx];
#pragma unroll
                        for (int tx = 0; tx < 4; ++tx)
                            acc[ty][tx] = fmaf(wv, f[ty + dy][tx + dx], acc[ty][tx]);
                    }
        }
    }
    if (valid) {
#pragma unroll
        for (int ty = 0; ty < 4; ++ty) {
            float* dst = out + ((size_t)b * C_TOT + 512 + co) * HW + (y0 + ty) * 28 + x0;
            *((float4*)dst) = make_float4(acc[ty][0], acc[ty][1], acc[ty][2], acc[ty][3]);
        }
    }
}

extern "C" void kernel_launch(void* const* d_in, const int* in_sizes, int n_in,
                              void* d_out, int out_size, void* d_ws, size_t ws_size,
                              hipStream_t stream) {
    const float* x       = (const float*)d_in[0];
    const float* bn1_w   = (const float*)d_in[1];
    const float* bn1_b   = (const float*)d_in[2];
    const float* conv1_w = (const float*)d_in[3];
    const float* rbn_w   = (const float*)d_in[4];
    const float* rbn_b   = (const float*)d_in[5];
    const float* conv2_w = (const float*)d_in[6];
    float* out = (float*)d_out;
    float* ws  = (float*)d_ws;   // needs ~26.3 MB

    k_stats_copy<<<dim3(512, 8), 256, 0, stream>>>(x, out, ws);
    k_prep1<<<1, 256, 0, stream>>>(bn1_w, bn1_b, conv1_w, rbn_w, rbn_b, conv2_w, ws);
    k_conv1<<<dim3(7, 64), 256, 0, stream>>>(x, ws);
    k_rbn_stats<<<dim3(128, 16), 256, 0, stream>>>(ws);
    k_prep2<<<1, 256, 0, stream>>>(ws);
    k_conv2<<<dim3(7, 64), 256, 0, stream>>>(out, ws);
}

// Round 2
// 244.260 us; speedup vs baseline: 1.3436x; 1.3436x over previous
//
#include <hip/hip_runtime.h>
#include <math.h>

// Dims: x[64,512,28,28] -> out[64,544,28,28] fp32
static constexpr int BB    = 64;
static constexpr int C_IN  = 512;
static constexpr int C_MID = 128;
static constexpr int C_OUT = 32;
static constexpr int C_TOT = 544;
static constexpr int HW    = 784;   // 28*28

// ---- workspace layout (float offsets). Total ~26.25 MB ----
static constexpr size_t H2_OFF    = 0;                         // 64*128*784 = 6,422,528
static constexpr size_t QW1_OFF   = 6422528;                   // bf16 [8][128][64] swizzled (32768 floats used)
static constexpr size_t QW2_OFF   = QW1_OFF + 65536;           // [ci][co][12] = 128*32*12
static constexpr size_t PSTAT_OFF = QW2_OFF + 49152;           // [512][8][4]
static constexpr size_t BNA_OFF   = PSTAT_OFF + 16384;         // 512
static constexpr size_t BNB_OFF   = BNA_OFF + 512;             // 512
static constexpr size_t CMAX_OFF  = BNB_OFF + 512;             // 128*16
static constexpr size_t CMIN_OFF  = CMAX_OFF + 2048;
static constexpr size_t CSUM_OFF  = CMIN_OFF + 2048;
static constexpr size_t A2_OFF    = CSUM_OFF + 2048;           // 128
static constexpr size_t B2_OFF    = A2_OFF + 128;
static constexpr size_t QRW_OFF   = B2_OFF + 128;
static constexpr size_t QRB_OFF   = QRW_OFF + 128;
static constexpr size_t SCAL_OFF  = QRB_OFF + 128;             // 16 scalars
// SCAL: 0=mn1 1=scale1 2=inv1 3=mn3 4=scale3 5=inv3 6=mx1 7=mx3

#define DEVFN __device__ __forceinline__

typedef __bf16 bf16x8 __attribute__((ext_vector_type(8)));
typedef float  f32x4  __attribute__((ext_vector_type(4)));

DEVFN float qact(float v, float mn, float mx, float inv, float sc) {
    v = fminf(fmaxf(v, mn), mx);
    return fmaf(rintf((v - mn) * inv), sc, mn);   // rintf == round-half-even == jnp.round
}

DEVFN unsigned f2bf(float f) {                    // fp32 -> bf16 bits, RNE (explicit, compiler-independent)
    unsigned u = __float_as_uint(f);
    return (u + 0x7fffu + ((u >> 16) & 1u)) >> 16;
}

DEVFN int swz(int col, int row) {  // XOR swizzle of 4-float groups (conv2 fp32 tiles)
    return (((col >> 2) ^ (row & 7)) << 2) | (col & 3);
}

// ---------- K0: per-channel x stats (8 image-groups) + concat copy out[:, :512] = x ----------
__global__ __launch_bounds__(256) void k_stats_copy(const float* __restrict__ x,
                                                    float* __restrict__ out,
                                                    float* __restrict__ ws) {
    const int c = blockIdx.x, bg = blockIdx.y, tid = threadIdx.x;
    float s = 0.f, s2 = 0.f, mn = INFINITY, mx = -INFINITY;
    for (int i = tid; i < 8 * 196; i += 256) {
        const int b = bg * 8 + i / 196, j = i % 196;
        const float4 v = ((const float4*)(x + ((size_t)b * C_IN + c) * HW))[j];
        ((float4*)(out + ((size_t)b * C_TOT + c) * HW))[j] = v;
        s  += (v.x + v.y) + (v.z + v.w);
        s2 += v.x * v.x + v.y * v.y + v.z * v.z + v.w * v.w;
        mn = fminf(mn, fminf(fminf(v.x, v.y), fminf(v.z, v.w)));
        mx = fmaxf(mx, fmaxf(fmaxf(v.x, v.y), fmaxf(v.z, v.w)));
    }
    __shared__ float r0[256], r1[256], r2[256], r3[256];
    r0[tid] = s; r1[tid] = s2; r2[tid] = mn; r3[tid] = mx;
    __syncthreads();
    for (int off = 128; off > 0; off >>= 1) {
        if (tid < off) {
            r0[tid] += r0[tid + off];
            r1[tid] += r1[tid + off];
            r2[tid] = fminf(r2[tid], r2[tid + off]);
            r3[tid] = fmaxf(r3[tid], r3[tid + off]);
        }
        __syncthreads();
    }
    if (tid == 0) {
        float* p = ws + PSTAT_OFF + ((size_t)c * 8 + bg) * 4;
        p[0] = r0[0]; p[1] = r1[0]; p[2] = r2[0]; p[3] = r3[0];
    }
}

// ---------- K1: BN coefs + h1 range + quantize all weights (conv1_w -> swizzled bf16) ----------
__global__ __launch_bounds__(256) void k_prep1(const float* __restrict__ bn1_w,
                                               const float* __restrict__ bn1_b,
                                               const float* __restrict__ conv1_w,
                                               const float* __restrict__ rbn_w,
                                               const float* __restrict__ rbn_b,
                                               const float* __restrict__ conv2_w,
                                               float* __restrict__ ws) {
    const int tid = threadIdx.x;
    __shared__ float ra[256], rb[256];
    __shared__ float s_mn, s_sc;

    // --- Phase A: per-channel BN affine + global h1 range via channel endpoints
    float lmn = INFINITY, lmx = -INFINITY;
    for (int c = tid; c < 512; c += 256) {
        const float* p = ws + PSTAT_OFF + (size_t)c * 32;
        float s = 0.f, s2 = 0.f, mn = INFINITY, mx = -INFINITY;
        for (int g = 0; g < 8; ++g) {
            s += p[g * 4 + 0]; s2 += p[g * 4 + 1];
            mn = fminf(mn, p[g * 4 + 2]); mx = fmaxf(mx, p[g * 4 + 3]);
        }
        const float n = 50176.f;
        const float mean = s / n;
        const float var  = s2 / n - mean * mean;
        const float rstd = rsqrtf(var + 1e-5f);
        const float A  = rstd * bn1_w[c];
        const float Bc = bn1_b[c] - mean * A;
        ws[BNA_OFF + c] = A; ws[BNB_OFF + c] = Bc;
        const float v1 = A * mn + Bc, v2 = A * mx + Bc;
        lmn = fminf(lmn, fmaxf(0.f, fminf(v1, v2)));
        lmx = fmaxf(lmx, fmaxf(0.f, fmaxf(v1, v2)));
    }
    ra[tid] = lmn; rb[tid] = lmx;
    __syncthreads();
    for (int off = 128; off > 0; off >>= 1) {
        if (tid < off) { ra[tid] = fminf(ra[tid], ra[tid + off]); rb[tid] = fmaxf(rb[tid], rb[tid + off]); }
        __syncthreads();
    }
    if (tid == 0) {
        const float mn1 = ra[0], mx1 = rb[0];
        const float sc = fmaxf((mx1 - mn1) / 255.f, 1e-8f);
        ws[SCAL_OFF + 0] = mn1; ws[SCAL_OFF + 1] = sc; ws[SCAL_OFF + 2] = 1.f / sc; ws[SCAL_OFF + 6] = mx1;
    }
    __syncthreads();

    // --- Phase B: quantize conv1_w -> bf16, layout [kstep8][co128][k64] with kc^=co&7 chunk swizzle
    {
        float mn = INFINITY, mx = -INFINITY;
        for (int i = tid; i < 16384; i += 256) {
            const float4 v = ((const float4*)conv1_w)[i];
            mn = fminf(mn, fminf(fminf(v.x, v.y), fminf(v.z, v.w)));
            mx = fmaxf(mx, fmaxf(fmaxf(v.x, v.y), fmaxf(v.z, v.w)));
        }
        ra[tid] = mn; rb[tid] = mx;
        __syncthreads();
        for (int off = 128; off > 0; off >>= 1) {
            if (tid < off) { ra[tid] = fminf(ra[tid], ra[tid + off]); rb[tid] = fmaxf(rb[tid], rb[tid + off]); }
            __syncthreads();
        }
        if (tid == 0) { s_mn = ra[0]; s_sc = fmaxf((rb[0] - ra[0]) / 255.f, 1e-8f); }
        __syncthreads();
        const float mnw = s_mn, scw = s_sc;
        unsigned short* qw = (unsigned short*)(ws + QW1_OFF);
        for (int i = tid; i < 65536; i += 256) {
            const int co = i >> 9, k = i & 511;
            const float v = conv1_w[i];
            const float qv = fmaf(rintf((v - mnw) / scw), scw, mnw);
            const int ks = k >> 6, kc = (k >> 3) & 7, klo = k & 7;
            qw[(((size_t)ks * 128 + co) << 6) + (((kc ^ (co & 7)) << 3) | klo)] = (unsigned short)f2bf(qv);
        }
        __syncthreads();
    }

    // --- Phase C: quantize conv2_w into padded [ci][co][12] layout (fp32)
    {
        float mn = INFINITY, mx = -INFINITY;
        for (int i = tid; i < 9216; i += 256) {
            const float4 v = ((const float4*)conv2_w)[i];
            mn = fminf(mn, fminf(fminf(v.x, v.y), fminf(v.z, v.w)));
            mx = fmaxf(mx, fmaxf(fmaxf(v.x, v.y), fmaxf(v.z, v.w)));
        }
        ra[tid] = mn; rb[tid] = mx;
        __syncthreads();
        for (int off = 128; off > 0; off >>= 1) {
            if (tid < off) { ra[tid] = fminf(ra[tid], ra[tid + off]); rb[tid] = fmaxf(rb[tid], rb[tid + off]); }
            __syncthreads();
        }
        if (tid == 0) { s_mn = ra[0]; s_sc = fmaxf((rb[0] - ra[0]) / 255.f, 1e-8f); }
        __syncthreads();
        const float mnw = s_mn, scw = s_sc;
        for (int i = tid; i < 36864; i += 256) {
            const int co = i / 1152, r = i % 1152, ci = r / 9, t = r % 9;
            const float v = conv2_w[i];
            ws[QW2_OFF + ((size_t)ci * 32 + co) * 12 + t] = fmaf(rintf((v - mnw) / scw), scw, mnw);
        }
        for (int i = tid; i < 4096; i += 256) {
            float* pz = ws + QW2_OFF + (size_t)i * 12;
            pz[9] = 0.f; pz[10] = 0.f; pz[11] = 0.f;
        }
        __syncthreads();
    }

    // --- Phase D: quantize rbn_w, rbn_b (128 each)
    for (int which = 0; which < 2; ++which) {
        const float* src = which ? rbn_b : rbn_w;
        const size_t dst = which ? QRB_OFF : QRW_OFF;
        float v = 0.f, mn = INFINITY, mx = -INFINITY;
        if (tid < 128) { v = src[tid]; mn = v; mx = v; }
        ra[tid] = mn; rb[tid] = mx;
        __syncthreads();
        for (int off = 128; off > 0; off >>= 1) {
            if (tid < off) { ra[tid] = fminf(ra[tid], ra[tid + off]); rb[tid] = fmaxf(rb[tid], rb[tid + off]); }
            __syncthreads();
        }
        if (tid == 0) { s_mn = ra[0]; s_sc = fmaxf((rb[0] - ra[0]) / 255.f, 1e-8f); }
        __syncthreads();
        if (tid < 128) ws[dst + tid] = fmaf(rintf((v - s_mn) / s_sc), s_sc, s_mn);
        __syncthreads();
    }
}

// ---------- K2: 1x1 conv as bf16 MFMA GEMM. M=128co, N=112p, K=512. BN+ReLU+quant fused on stage ----------
__global__ __launch_bounds__(256, 2) void k_conv1(const float* __restrict__ x, float* __restrict__ ws) {
    __shared__ __align__(16) unsigned short wt[128 * 64];   // [co][k64], chunk-swizzled, 16 KB
    __shared__ __align__(16) unsigned short ht[112 * 64];   // [p][k64],  chunk-swizzled, 14 KB
    const int tid = threadIdx.x;
    const int pt = blockIdx.x, b = blockIdx.y;               // p-tile 0..6 (112 wide), batch
    const int p0 = pt * 112;
    const float mn1 = ws[SCAL_OFF + 0], sc1 = ws[SCAL_OFF + 1];
    const float inv1 = ws[SCAL_OFF + 2], mx1 = ws[SCAL_OFF + 6];
    const unsigned short* qw1 = (const unsigned short*)(ws + QW1_OFF);
    const float* xb = x + (size_t)b * C_IN * HW;

    const int o = tid & 7, q = tid >> 3;                     // staging: 8 ci-octs x 28 p-quads (224 active)
    const int wv = tid >> 6, g = (tid >> 4) & 3, r4 = tid & 15;  // compute: wave, k-group, frag index

    f32x4 acc[2][7];
#pragma unroll
    for (int i = 0; i < 2; ++i)
#pragma unroll
        for (int j = 0; j < 7; ++j) acc[i][j] = f32x4{0.f, 0.f, 0.f, 0.f};

    for (int ks = 0; ks < 8; ++ks) {                         // K-steps of 64
        // stage weights: 16 KB contiguous (pre-swizzled in prep)
        const float4* wsrc = (const float4*)(qw1 + (size_t)ks * 8192);
        float4* wdst = (float4*)wt;
#pragma unroll
        for (int i = 0; i < 4; ++i) wdst[tid + i * 256] = wsrc[tid + i * 256];

        // stage activations with fused BN+ReLU+quant and register 8k x 4p transpose
        if (tid < 224) {
            const int ci0 = ks * 64 + o * 8;
            float vv[8][4];
#pragma unroll
            for (int j = 0; j < 8; ++j) {
                const float4 v = *(const float4*)(xb + (size_t)(ci0 + j) * HW + p0 + q * 4);
                const float A = ws[BNA_OFF + ci0 + j], Bc = ws[BNB_OFF + ci0 + j];
                vv[j][0] = qact(fmaxf(0.f, fmaf(v.x, A, Bc)), mn1, mx1, inv1, sc1);
                vv[j][1] = qact(fmaxf(0.f, fmaf(v.y, A, Bc)), mn1, mx1, inv1, sc1);
                vv[j][2] = qact(fmaxf(0.f, fmaf(v.z, A, Bc)), mn1, mx1, inv1, sc1);
                vv[j][3] = qact(fmaxf(0.f, fmaf(v.w, A, Bc)), mn1, mx1, inv1, sc1);
            }
#pragma unroll
            for (int r = 0; r < 4; ++r) {
                const int p = q * 4 + r;
                uint4 pk;
                pk.x = f2bf(vv[0][r]) | (f2bf(vv[1][r]) << 16);
                pk.y = f2bf(vv[2][r]) | (f2bf(vv[3][r]) << 16);
                pk.z = f2bf(vv[4][r]) | (f2bf(vv[5][r]) << 16);
                pk.w = f2bf(vv[6][r]) | (f2bf(vv[7][r]) << 16);
                *(uint4*)&ht[p * 64 + ((o ^ (p & 7)) << 3)] = pk;
            }
        }
        __syncthreads();

#pragma unroll
        for (int ksub = 0; ksub < 2; ++ksub) {
            const int kk = ksub * 4 + g;                     // k-chunk index 0..7
            bf16x8 af[2], bfr[7];
#pragma unroll
            for (int ct = 0; ct < 2; ++ct) {
                const int co = wv * 32 + ct * 16 + r4;
                af[ct] = *(const bf16x8*)&wt[co * 64 + ((kk ^ (co & 7)) << 3)];
            }
#pragma unroll
            for (int pf = 0; pf < 7; ++pf) {
                const int p = pf * 16 + r4;
                bfr[pf] = *(const bf16x8*)&ht[p * 64 + ((kk ^ (p & 7)) << 3)];
            }
#pragma unroll
            for (int ct = 0; ct < 2; ++ct)
#pragma unroll
                for (int pf = 0; pf < 7; ++pf)
                    acc[ct][pf] = __builtin_amdgcn_mfma_f32_16x16x32_bf16(af[ct], bfr[pf], acc[ct][pf], 0, 0, 0);
        }
        __syncthreads();
    }

    // epilogue: C row = co = (lane>>4)*4 + reg (+16*ct +32*wave), col = p = lane&15 (+16*pf)
    float* hb = ws + H2_OFF + (size_t)b * C_MID * HW;
#pragma unroll
    for (int ct = 0; ct < 2; ++ct) {
        const int co0 = wv * 32 + ct * 16 + g * 4;
#pragma unroll
        for (int pf = 0; pf < 7; ++pf) {
            const int p = p0 + pf * 16 + r4;
#pragma unroll
            for (int r = 0; r < 4; ++r)
                hb[(size_t)(co0 + r) * HW + p] = acc[ct][pf][r];
        }
    }
}

// ---------- K3: RangeBN chunked stats: chunk = 4 consecutive images ----------
__global__ __launch_bounds__(256) void k_rbn_stats(float* __restrict__ ws) {
    const int c = blockIdx.x, ch = blockIdx.y, tid = threadIdx.x;
    float s = 0.f, mn = INFINITY, mx = -INFINITY;
    for (int i = tid; i < 784; i += 256) {
        const int b = ch * 4 + i / 196, j = i % 196;
        const float4 v = ((const float4*)(ws + H2_OFF + ((size_t)b * C_MID + c) * HW))[j];
        s += (v.x + v.y) + (v.z + v.w);
        mn = fminf(mn, fminf(fminf(v.x, v.y), fminf(v.z, v.w)));
        mx = fmaxf(mx, fmaxf(fmaxf(v.x, v.y), fmaxf(v.z, v.w)));
    }
    __shared__ float r0[256], r1[256], r2[256];
    r0[tid] = s; r1[tid] = mn; r2[tid] = mx;
    __syncthreads();
    for (int off = 128; off > 0; off >>= 1) {
        if (tid < off) {
            r0[tid] += r0[tid + off];
            r1[tid] = fminf(r1[tid], r1[tid + off]);
            r2[tid] = fmaxf(r2[tid], r2[tid + off]);
        }
        __syncthreads();
    }
    if (tid == 0) {
        ws[CSUM_OFF + (size_t)c * 16 + ch] = r0[0];
        ws[CMIN_OFF + (size_t)c * 16 + ch] = r1[0];
        ws[CMAX_OFF + (size_t)c * 16 + ch] = r2[0];
    }
}

// ---------- K4: RangeBN affine + h3 range ----------
__global__ __launch_bounds__(256) void k_prep2(float* __restrict__ ws) {
    const int tid = threadIdx.x;
    __shared__ float ra[256], rb[256];
    float lo = INFINITY, hi = -INFINITY;
    if (tid < 128) {
        const int c = tid;
        float mm = 0.f, mnm = 0.f, s = 0.f, cmx = -INFINITY, cmn = INFINITY;
        for (int ch = 0; ch < 16; ++ch) {
            const float a = ws[CMAX_OFF + (size_t)c * 16 + ch];
            const float m = ws[CMIN_OFF + (size_t)c * 16 + ch];
            mm += a; mnm += m; s += ws[CSUM_OFF + (size_t)c * 16 + ch];
            cmx = fmaxf(cmx, a); cmn = fminf(cmn, m);
        }
        mm *= (1.f / 16.f); mnm *= (1.f / 16.f);
        const float mean = s / 50176.f;
        const double PI_D = 3.14159265358979323846;
        const double sfd = 0.175 * (1.0 + sqrt(PI_D * log(4.0))) / sqrt(2.0 * log(3136.0));
        const float scale = 1.f / ((mm - mnm) * (float)sfd + 1e-5f);
        const float A  = scale * ws[QRW_OFF + c];
        const float Bc = ws[QRB_OFF + c] - mean * A;
        ws[A2_OFF + c] = A; ws[B2_OFF + c] = Bc;
        const float v1 = A * cmn + Bc, v2 = A * cmx + Bc;
        lo = fmaxf(0.f, fminf(v1, v2));
        hi = fmaxf(0.f, fmaxf(v1, v2));
    }
    ra[tid] = lo; rb[tid] = hi;
    __syncthreads();
    for (int off = 128; off > 0; off >>= 1) {
        if (tid < off) { ra[tid] = fminf(ra[tid], ra[tid + off]); rb[tid] = fmaxf(rb[tid], rb[tid + off]); }
        __syncthreads();
    }
    if (tid == 0) {
        const float mn3 = ra[0], mx3 = rb[0];
        const float sc = fmaxf((mx3 - mn3) / 255.f, 1e-8f);
        ws[SCAL_OFF + 3] = mn3; ws[SCAL_OFF + 4] = sc; ws[SCAL_OFF + 5] = 1.f / sc; ws[SCAL_OFF + 7] = mx3;
    }
}

// ---------- K5: 3x3 conv fp32, RBN+ReLU+quant fused in staging, writes out[:, 512:544] ----------
__global__ __launch_bounds__(256, 2) void k_conv2(float* __restrict__ out, const float* __restrict__ ws) {
    __shared__ __align__(16) float win[8 * 32 * 12];   // [ci][co][12]
    __shared__ __align__(16) float inb[8 * 12 * 32];   // [ci][row][32], XOR-swizzled cols
    const int tid = threadIdx.x;
    const int qg = blockIdx.x, b = blockIdx.y;
    const int co = tid & 31, q = tid >> 5;
    int gq = qg * 8 + q;
    const bool valid = gq < 49;
    if (!valid) gq = 48;
    const int qy = gq / 7, qx = gq % 7;
    const int y0 = qy * 4, x0 = qx * 4;
    const int ylo = ((qg * 8) / 7) * 4;
    const int r0 = y0 - ylo;
    const float mn3 = ws[SCAL_OFF + 3], sc3 = ws[SCAL_OFF + 4];
    const float inv3 = ws[SCAL_OFF + 5], mx3 = ws[SCAL_OFF + 7];
    float acc[4][4];
#pragma unroll
    for (int i = 0; i < 4; ++i)
#pragma unroll
        for (int j = 0; j < 4; ++j) acc[i][j] = 0.f;

    for (int cc = 0; cc < 16; ++cc) {
        const int ci0 = cc * 8;
        __syncthreads();
        for (int i = tid; i < 768; i += 256)
            ((float4*)win)[i] = ((const float4*)(ws + QW2_OFF + (size_t)ci0 * 384))[i];
        if (tid < 96) {
            const int ci = tid / 12, rr = tid % 12;
            const int r = ylo + rr;
            float* dst = inb + (ci * 12 + rr) * 32;
            if (r <= 29) {
                if (r == 0 || r == 29) {
#pragma unroll
                    for (int cj = 0; cj < 32; ++cj) dst[swz(cj, rr)] = 0.f;
                } else {
                    const float A = ws[A2_OFF + ci0 + ci], Bc = ws[B2_OFF + ci0 + ci];
                    const float* src = ws + H2_OFF + ((size_t)b * C_MID + ci0 + ci) * HW + (r - 1) * 28;
                    dst[swz(0, rr)]  = 0.f;
                    dst[swz(29, rr)] = 0.f; dst[swz(30, rr)] = 0.f; dst[swz(31, rr)] = 0.f;
#pragma unroll
                    for (int j = 0; j < 7; ++j) {
                        const float4 v = ((const float4*)src)[j];
                        dst[swz(1 + j * 4 + 0, rr)] = qact(fmaxf(0.f, fmaf(v.x, A, Bc)), mn3, mx3, inv3, sc3);
                        dst[swz(1 + j * 4 + 1, rr)] = qact(fmaxf(0.f, fmaf(v.y, A, Bc)), mn3, mx3, inv3, sc3);
                        dst[swz(1 + j * 4 + 2, rr)] = qact(fmaxf(0.f, fmaf(v.z, A, Bc)), mn3, mx3, inv3, sc3);
                        dst[swz(1 + j * 4 + 3, rr)] = qact(fmaxf(0.f, fmaf(v.w, A, Bc)), mn3, mx3, inv3, sc3);
                    }
                }
            }
        }
        __syncthreads();
#pragma unroll
        for (int ci = 0; ci < 8; ++ci) {
            const float* wp = win + ((size_t)ci * 32 + co) * 12;
            const float4 w0 = *((const float4*)wp);
            const float4 w1 = *((const float4*)(wp + 4));
            const float  w8 = wp[8];
            const float w9[9] = {w0.x, w0.y, w0.z, w0.w, w1.x, w1.y, w1.z, w1.w, w8};
            float f[6][8];
#pragma unroll
            for (int rr2 = 0; rr2 < 6; ++rr2) {
                const int rl = r0 + rr2;
                const float* rowp = inb + (ci * 12 + rl) * 32;
                const float4 va = *((const float4*)(rowp + ((qx ^ (rl & 7)) << 2)));
                const float4 vb = *((const float4*)(rowp + (((qx + 1) ^ (rl & 7)) << 2)));
                f[rr2][0] = va.x; f[rr2][1] = va.y; f[rr2][2] = va.z; f[rr2][3] = va.w;
                f[rr2][4] = vb.x; f[rr2][5] = vb.y; f[rr2][6] = vb.z; f[rr2][7] = vb.w;
            }
#pragma unroll
            for (int ty = 0; ty < 4; ++ty)
#pragma unroll
                for (int dy = 0; dy < 3; ++dy)
#pragma unroll
                    for (int dx = 0; dx < 3; ++dx) {
                        const float wv = w9[dy * 3 + dx];
#pragma unroll
                        for (int tx = 0; tx < 4; ++tx)
                            acc[ty][tx] = fmaf(wv, f[ty + dy][tx + dx], acc[ty][tx]);
                    }
        }
    }
    if (valid) {
#pragma unroll
        for (int ty = 0; ty < 4; ++ty) {
            float* dst = out + ((size_t)b * C_TOT + 512 + co) * HW + (y0 + ty) * 28 + x0;
            *((float4*)dst) = make_float4(acc[ty][0], acc[ty][1], acc[ty][2], acc[ty][3]);
        }
    }
}

extern "C" void kernel_launch(void* const* d_in, const int* in_sizes, int n_in,
                              void* d_out, int out_size, void* d_ws, size_t ws_size,
                              hipStream_t stream) {
    const float* x       = (const float*)d_in[0];
    const float* bn1_w   = (const float*)d_in[1];
    const float* bn1_b   = (const float*)d_in[2];
    const float* conv1_w = (const float*)d_in[3];
    const float* rbn_w   = (const float*)d_in[4];
    const float* rbn_b   = (const float*)d_in[5];
    const float* conv2_w = (const float*)d_in[6];
    float* out = (float*)d_out;
    float* ws  = (float*)d_ws;

    k_stats_copy<<<dim3(512, 8), 256, 0, stream>>>(x, out, ws);
    k_prep1<<<1, 256, 0, stream>>>(bn1_w, bn1_b, conv1_w, rbn_w, rbn_b, conv2_w, ws);
    k_conv1<<<dim3(7, 64), 256, 0, stream>>>(x, ws);
    k_rbn_stats<<<dim3(128, 16), 256, 0, stream>>>(ws);
    k_prep2<<<1, 256, 0, stream>>>(ws);
    k_conv2<<<dim3(7, 64), 256, 0, stream>>>(out, ws);
}

// Round 3
// 171.110 us; speedup vs baseline: 1.9180x; 1.4275x over previous
//
#include <hip/hip_runtime.h>
#include <math.h>

// Dims: x[64,512,28,28] -> out[64,544,28,28] fp32
static constexpr int BB    = 64;
static constexpr int C_IN  = 512;
static constexpr int C_MID = 128;
static constexpr int C_OUT = 32;
static constexpr int C_TOT = 544;
static constexpr int HW    = 784;   // 28*28

// ---- workspace layout (float offsets). Total ~26.25 MB ----
static constexpr size_t H2_OFF    = 0;                         // 64*128*784 = 6,422,528
static constexpr size_t QW1_OFF   = 6422528;                   // bf16 [8][128][64] swizzled (32768 floats used)
static constexpr size_t QW2_OFF   = QW1_OFF + 65536;           // [ci][co][12] = 128*32*12
static constexpr size_t PSTAT_OFF = QW2_OFF + 49152;           // [512][8][4]
static constexpr size_t BNA_OFF   = PSTAT_OFF + 16384;         // 512
static constexpr size_t BNB_OFF   = BNA_OFF + 512;             // 512
static constexpr size_t CMAX_OFF  = BNB_OFF + 512;             // 128*16
static constexpr size_t CMIN_OFF  = CMAX_OFF + 2048;
static constexpr size_t CSUM_OFF  = CMIN_OFF + 2048;
static constexpr size_t A2_OFF    = CSUM_OFF + 2048;           // 128
static constexpr size_t B2_OFF    = A2_OFF + 128;
static constexpr size_t QRW_OFF   = B2_OFF + 128;
static constexpr size_t QRB_OFF   = QRW_OFF + 128;
static constexpr size_t SCAL_OFF  = QRB_OFF + 128;             // 16 scalars
// SCAL: 0=mn1 1=scale1 2=inv1 3=mn3 4=scale3 5=inv3 6=mx1 7=mx3
//       8=mn_w1 9=sc_w1 10=mn_w2 11=sc_w2
static constexpr size_t PART_OFF  = SCAL_OFF + 16;             // partials: conv1 64, conv2 16, h1 8

#define DEVFN __device__ __forceinline__

typedef __bf16 bf16x8 __attribute__((ext_vector_type(8)));
typedef float  f32x4  __attribute__((ext_vector_type(4)));

DEVFN float qact(float v, float mn, float mx, float inv, float sc) {
    v = fminf(fmaxf(v, mn), mx);
    return fmaf(rintf((v - mn) * inv), sc, mn);   // rintf == round-half-even == jnp.round
}

DEVFN unsigned f2bf(float f) {                    // fp32 -> bf16 bits, RNE
    unsigned u = __float_as_uint(f);
    return (u + 0x7fffu + ((u >> 16) & 1u)) >> 16;
}

DEVFN int swz(int col, int row) {  // XOR swizzle of 4-float groups (conv2 fp32 tiles)
    return (((col >> 2) ^ (row & 7)) << 2) | (col & 3);
}

// ---------- K0: per-channel x stats (8 image-groups) + concat copy out[:, :512] = x ----------
__global__ __launch_bounds__(256) void k_stats_copy(const float* __restrict__ x,
                                                    float* __restrict__ out,
                                                    float* __restrict__ ws) {
    const int c = blockIdx.x, bg = blockIdx.y, tid = threadIdx.x;
    float s = 0.f, s2 = 0.f, mn = INFINITY, mx = -INFINITY;
    for (int i = tid; i < 8 * 196; i += 256) {
        const int b = bg * 8 + i / 196, j = i % 196;
        const float4 v = ((const float4*)(x + ((size_t)b * C_IN + c) * HW))[j];
        ((float4*)(out + ((size_t)b * C_TOT + c) * HW))[j] = v;
        s  += (v.x + v.y) + (v.z + v.w);
        s2 += v.x * v.x + v.y * v.y + v.z * v.z + v.w * v.w;
        mn = fminf(mn, fminf(fminf(v.x, v.y), fminf(v.z, v.w)));
        mx = fmaxf(mx, fmaxf(fmaxf(v.x, v.y), fmaxf(v.z, v.w)));
    }
    __shared__ float r0[256], r1[256], r2[256], r3[256];
    r0[tid] = s; r1[tid] = s2; r2[tid] = mn; r3[tid] = mx;
    __syncthreads();
    for (int off = 128; off > 0; off >>= 1) {
        if (tid < off) {
            r0[tid] += r0[tid + off];
            r1[tid] += r1[tid + off];
            r2[tid] = fminf(r2[tid], r2[tid + off]);
            r3[tid] = fmaxf(r3[tid], r3[tid + off]);
        }
        __syncthreads();
    }
    if (tid == 0) {
        float* p = ws + PSTAT_OFF + ((size_t)c * 8 + bg) * 4;
        p[0] = r0[0]; p[1] = r1[0]; p[2] = r2[0]; p[3] = r3[0];
    }
}

// ---------- K1a: parallel reductions — conv1_w/conv2_w min-max partials + BN phase A ----------
__global__ __launch_bounds__(256) void k_prep_red(const float* __restrict__ conv1_w,
                                                  const float* __restrict__ conv2_w,
                                                  const float* __restrict__ bn1_w,
                                                  const float* __restrict__ bn1_b,
                                                  float* __restrict__ ws) {
    const int b = blockIdx.x, tid = threadIdx.x;
    __shared__ float ra[256], rb[256];
    float mn = INFINITY, mx = -INFINITY;

    if (b < 32) {                                  // conv1_w: 2048 floats per block
        const float4* src = (const float4*)conv1_w + (size_t)b * 512;
        for (int i = tid; i < 512; i += 256) {
            const float4 v = src[i];
            mn = fminf(mn, fminf(fminf(v.x, v.y), fminf(v.z, v.w)));
            mx = fmaxf(mx, fmaxf(fmaxf(v.x, v.y), fmaxf(v.z, v.w)));
        }
    } else if (b < 40) {                           // conv2_w: 4608 floats per block
        const float4* src = (const float4*)conv2_w + (size_t)(b - 32) * 1152;
        for (int i = tid; i < 1152; i += 256) {
            const float4 v = src[i];
            mn = fminf(mn, fminf(fminf(v.x, v.y), fminf(v.z, v.w)));
            mx = fmaxf(mx, fmaxf(fmaxf(v.x, v.y), fmaxf(v.z, v.w)));
        }
    } else {                                       // BN phase A: 128 channels per block
        if (tid < 128) {
            const int c = (b - 40) * 128 + tid;
            const float* p = ws + PSTAT_OFF + (size_t)c * 32;
            float s = 0.f, s2 = 0.f, cmn = INFINITY, cmx = -INFINITY;
            for (int g = 0; g < 8; ++g) {
                s += p[g * 4 + 0]; s2 += p[g * 4 + 1];
                cmn = fminf(cmn, p[g * 4 + 2]); cmx = fmaxf(cmx, p[g * 4 + 3]);
            }
            const float n = 50176.f;
            const float mean = s / n;
            const float var  = s2 / n - mean * mean;
            const float rstd = rsqrtf(var + 1e-5f);
            const float A  = rstd * bn1_w[c];
            const float Bc = bn1_b[c] - mean * A;
            ws[BNA_OFF + c] = A; ws[BNB_OFF + c] = Bc;
            const float v1 = A * cmn + Bc, v2 = A * cmx + Bc;
            mn = fmaxf(0.f, fminf(v1, v2));
            mx = fmaxf(0.f, fmaxf(v1, v2));
        }
    }
    ra[tid] = mn; rb[tid] = mx;
    __syncthreads();
    for (int off = 128; off > 0; off >>= 1) {
        if (tid < off) { ra[tid] = fminf(ra[tid], ra[tid + off]); rb[tid] = fmaxf(rb[tid], rb[tid + off]); }
        __syncthreads();
    }
    if (tid == 0) {
        float* p;
        if (b < 32)       p = ws + PART_OFF + (size_t)b * 2;
        else if (b < 40)  p = ws + PART_OFF + 64 + (size_t)(b - 32) * 2;
        else              p = ws + PART_OFF + 80 + (size_t)(b - 40) * 2;
        p[0] = ra[0]; p[1] = rb[0];
    }
}

// ---------- K1b: finalize scales + quantize rbn params ----------
__global__ __launch_bounds__(256) void k_prep_fin(const float* __restrict__ rbn_w,
                                                  const float* __restrict__ rbn_b,
                                                  float* __restrict__ ws) {
    const int tid = threadIdx.x;
    __shared__ float ra[256], rb[256];
    __shared__ float s_mn, s_sc;

    // conv1_w scale (32 partials)
    ra[tid] = tid < 32 ? ws[PART_OFF + tid * 2] : INFINITY;
    rb[tid] = tid < 32 ? ws[PART_OFF + tid * 2 + 1] : -INFINITY;
    __syncthreads();
    for (int off = 128; off > 0; off >>= 1) {
        if (tid < off) { ra[tid] = fminf(ra[tid], ra[tid + off]); rb[tid] = fmaxf(rb[tid], rb[tid + off]); }
        __syncthreads();
    }
    if (tid == 0) {
        ws[SCAL_OFF + 8] = ra[0];
        ws[SCAL_OFF + 9] = fmaxf((rb[0] - ra[0]) / 255.f, 1e-8f);
    }
    __syncthreads();

    // conv2_w scale (8 partials)
    ra[tid] = tid < 8 ? ws[PART_OFF + 64 + tid * 2] : INFINITY;
    rb[tid] = tid < 8 ? ws[PART_OFF + 64 + tid * 2 + 1] : -INFINITY;
    __syncthreads();
    for (int off = 128; off > 0; off >>= 1) {
        if (tid < off) { ra[tid] = fminf(ra[tid], ra[tid + off]); rb[tid] = fmaxf(rb[tid], rb[tid + off]); }
        __syncthreads();
    }
    if (tid == 0) {
        ws[SCAL_OFF + 10] = ra[0];
        ws[SCAL_OFF + 11] = fmaxf((rb[0] - ra[0]) / 255.f, 1e-8f);
    }
    __syncthreads();

    // h1 range (4 partials)
    ra[tid] = tid < 4 ? ws[PART_OFF + 80 + tid * 2] : INFINITY;
    rb[tid] = tid < 4 ? ws[PART_OFF + 80 + tid * 2 + 1] : -INFINITY;
    __syncthreads();
    for (int off = 128; off > 0; off >>= 1) {
        if (tid < off) { ra[tid] = fminf(ra[tid], ra[tid + off]); rb[tid] = fmaxf(rb[tid], rb[tid + off]); }
        __syncthreads();
    }
    if (tid == 0) {
        const float mn1 = ra[0], mx1 = rb[0];
        const float sc = fmaxf((mx1 - mn1) / 255.f, 1e-8f);
        ws[SCAL_OFF + 0] = mn1; ws[SCAL_OFF + 1] = sc; ws[SCAL_OFF + 2] = 1.f / sc; ws[SCAL_OFF + 6] = mx1;
    }
    __syncthreads();

    // rbn_w / rbn_b quantize (128 each)
    for (int which = 0; which < 2; ++which) {
        const float* src = which ? rbn_b : rbn_w;
        const size_t dst = which ? QRB_OFF : QRW_OFF;
        float v = 0.f;
        ra[tid] = INFINITY; rb[tid] = -INFINITY;
        if (tid < 128) { v = src[tid]; ra[tid] = v; rb[tid] = v; }
        __syncthreads();
        for (int off = 128; off > 0; off >>= 1) {
            if (tid < off) { ra[tid] = fminf(ra[tid], ra[tid + off]); rb[tid] = fmaxf(rb[tid], rb[tid + off]); }
            __syncthreads();
        }
        if (tid == 0) { s_mn = ra[0]; s_sc = fmaxf((rb[0] - ra[0]) / 255.f, 1e-8f); }
        __syncthreads();
        if (tid < 128) ws[dst + tid] = fmaf(rintf((v - s_mn) / s_sc), s_sc, s_mn);
        __syncthreads();
    }
}

// ---------- K1c: parallel weight quantize ----------
__global__ __launch_bounds__(256) void k_prep_quant(const float* __restrict__ conv1_w,
                                                    const float* __restrict__ conv2_w,
                                                    float* __restrict__ ws) {
    const int b = blockIdx.x, tid = threadIdx.x;
    if (b < 32) {                                  // conv1_w -> bf16 swizzled [ks][co][k64]
        const float mnw = ws[SCAL_OFF + 8], scw = ws[SCAL_OFF + 9];
        unsigned short* qw = (unsigned short*)(ws + QW1_OFF);
        const int base = b * 2048;
#pragma unroll
        for (int t = 0; t < 8; ++t) {
            const int i = base + t * 256 + tid;
            const int co = i >> 9, k = i & 511;
            const float v = conv1_w[i];
            const float qv = fmaf(rintf((v - mnw) / scw), scw, mnw);
            const int ks = k >> 6, kc = (k >> 3) & 7, klo = k & 7;
            qw[(((size_t)ks * 128 + co) << 6) + (((kc ^ (co & 7)) << 3) | klo)] = (unsigned short)f2bf(qv);
        }
    } else {                                       // conv2_w -> padded [ci][co][12] fp32
        const float mnw = ws[SCAL_OFF + 10], scw = ws[SCAL_OFF + 11];
        const int base = (b - 32) * 4608;
        for (int i2 = tid; i2 < 4608; i2 += 256) {
            const int i = base + i2;
            const int co = i / 1152, r = i % 1152, ci = r / 9, t = r % 9;
            const float v = conv2_w[i];
            ws[QW2_OFF + ((size_t)ci * 32 + co) * 12 + t] = fmaf(rintf((v - mnw) / scw), scw, mnw);
        }
        for (int i2 = tid; i2 < 512; i2 += 256) {  // zero pads: 512 triplets per block
            float* pz = ws + QW2_OFF + (size_t)((b - 32) * 512 + i2) * 12;
            pz[9] = 0.f; pz[10] = 0.f; pz[11] = 0.f;
        }
    }
}

// ---------- K2: 1x1 conv as bf16 MFMA GEMM. M=128co, N=112p, K=512. BN+ReLU+quant fused on stage ----------
__global__ __launch_bounds__(256, 2) void k_conv1(const float* __restrict__ x, float* __restrict__ ws) {
    __shared__ __align__(16) unsigned short wt[128 * 64];   // [co][k64], chunk-swizzled, 16 KB
    __shared__ __align__(16) unsigned short ht[112 * 64];   // [p][k64],  chunk-swizzled, 14 KB
    const int tid = threadIdx.x;
    const int pt = blockIdx.x, b = blockIdx.y;               // p-tile 0..6 (112 wide), batch
    const int p0 = pt * 112;
    const float mn1 = ws[SCAL_OFF + 0], sc1 = ws[SCAL_OFF + 1];
    const float inv1 = ws[SCAL_OFF + 2], mx1 = ws[SCAL_OFF + 6];
    const unsigned short* qw1 = (const unsigned short*)(ws + QW1_OFF);
    const float* xb = x + (size_t)b * C_IN * HW;

    const int o = tid & 7, q = tid >> 3;                     // staging: 8 ci-octs x 28 p-quads (224 active)
    const int wv = tid >> 6, g = (tid >> 4) & 3, r4 = tid & 15;  // compute: wave, k-group, frag index

    f32x4 acc[2][7];
#pragma unroll
    for (int i = 0; i < 2; ++i)
#pragma unroll
        for (int j = 0; j < 7; ++j) acc[i][j] = f32x4{0.f, 0.f, 0.f, 0.f};

    for (int ks = 0; ks < 8; ++ks) {                         // K-steps of 64
        const float4* wsrc = (const float4*)(qw1 + (size_t)ks * 8192);
        float4* wdst = (float4*)wt;
#pragma unroll
        for (int i = 0; i < 4; ++i) wdst[tid + i * 256] = wsrc[tid + i * 256];

        if (tid < 224) {
            const int ci0 = ks * 64 + o * 8;
            float vv[8][4];
#pragma unroll
            for (int j = 0; j < 8; ++j) {
                const float4 v = *(const float4*)(xb + (size_t)(ci0 + j) * HW + p0 + q * 4);
                const float A = ws[BNA_OFF + ci0 + j], Bc = ws[BNB_OFF + ci0 + j];
                vv[j][0] = qact(fmaxf(0.f, fmaf(v.x, A, Bc)), mn1, mx1, inv1, sc1);
                vv[j][1] = qact(fmaxf(0.f, fmaf(v.y, A, Bc)), mn1, mx1, inv1, sc1);
                vv[j][2] = qact(fmaxf(0.f, fmaf(v.z, A, Bc)), mn1, mx1, inv1, sc1);
                vv[j][3] = qact(fmaxf(0.f, fmaf(v.w, A, Bc)), mn1, mx1, inv1, sc1);
            }
#pragma unroll
            for (int r = 0; r < 4; ++r) {
                const int p = q * 4 + r;
                uint4 pk;
                pk.x = f2bf(vv[0][r]) | (f2bf(vv[1][r]) << 16);
                pk.y = f2bf(vv[2][r]) | (f2bf(vv[3][r]) << 16);
                pk.z = f2bf(vv[4][r]) | (f2bf(vv[5][r]) << 16);
                pk.w = f2bf(vv[6][r]) | (f2bf(vv[7][r]) << 16);
                *(uint4*)&ht[p * 64 + ((o ^ (p & 7)) << 3)] = pk;
            }
        }
        __syncthreads();

#pragma unroll
        for (int ksub = 0; ksub < 2; ++ksub) {
            const int kk = ksub * 4 + g;
            bf16x8 af[2], bfr[7];
#pragma unroll
            for (int ct = 0; ct < 2; ++ct) {
                const int co = wv * 32 + ct * 16 + r4;
                af[ct] = *(const bf16x8*)&wt[co * 64 + ((kk ^ (co & 7)) << 3)];
            }
#pragma unroll
            for (int pf = 0; pf < 7; ++pf) {
                const int p = pf * 16 + r4;
                bfr[pf] = *(const bf16x8*)&ht[p * 64 + ((kk ^ (p & 7)) << 3)];
            }
#pragma unroll
            for (int ct = 0; ct < 2; ++ct)
#pragma unroll
                for (int pf = 0; pf < 7; ++pf)
                    acc[ct][pf] = __builtin_amdgcn_mfma_f32_16x16x32_bf16(af[ct], bfr[pf], acc[ct][pf], 0, 0, 0);
        }
        __syncthreads();
    }

    float* hb = ws + H2_OFF + (size_t)b * C_MID * HW;
#pragma unroll
    for (int ct = 0; ct < 2; ++ct) {
        const int co0 = wv * 32 + ct * 16 + g * 4;
#pragma unroll
        for (int pf = 0; pf < 7; ++pf) {
            const int p = p0 + pf * 16 + r4;
#pragma unroll
            for (int r = 0; r < 4; ++r)
                hb[(size_t)(co0 + r) * HW + p] = acc[ct][pf][r];
        }
    }
}

// ---------- K3: RangeBN chunked stats: chunk = 4 consecutive images ----------
__global__ __launch_bounds__(256) void k_rbn_stats(float* __restrict__ ws) {
    const int c = blockIdx.x, ch = blockIdx.y, tid = threadIdx.x;
    float s = 0.f, mn = INFINITY, mx = -INFINITY;
    for (int i = tid; i < 784; i += 256) {
        const int b = ch * 4 + i / 196, j = i % 196;
        const float4 v = ((const float4*)(ws + H2_OFF + ((size_t)b * C_MID + c) * HW))[j];
        s += (v.x + v.y) + (v.z + v.w);
        mn = fminf(mn, fminf(fminf(v.x, v.y), fminf(v.z, v.w)));
        mx = fmaxf(mx, fmaxf(fmaxf(v.x, v.y), fmaxf(v.z, v.w)));
    }
    __shared__ float r0[256], r1[256], r2[256];
    r0[tid] = s; r1[tid] = mn; r2[tid] = mx;
    __syncthreads();
    for (int off = 128; off > 0; off >>= 1) {
        if (tid < off) {
            r0[tid] += r0[tid + off];
            r1[tid] = fminf(r1[tid], r1[tid + off]);
            r2[tid] = fmaxf(r2[tid], r2[tid + off]);
        }
        __syncthreads();
    }
    if (tid == 0) {
        ws[CSUM_OFF + (size_t)c * 16 + ch] = r0[0];
        ws[CMIN_OFF + (size_t)c * 16 + ch] = r1[0];
        ws[CMAX_OFF + (size_t)c * 16 + ch] = r2[0];
    }
}

// ---------- K4: RangeBN affine + h3 range ----------
__global__ __launch_bounds__(256) void k_prep2(float* __restrict__ ws) {
    const int tid = threadIdx.x;
    __shared__ float ra[256], rb[256];
    float lo = INFINITY, hi = -INFINITY;
    if (tid < 128) {
        const int c = tid;
        float mm = 0.f, mnm = 0.f, s = 0.f, cmx = -INFINITY, cmn = INFINITY;
        for (int ch = 0; ch < 16; ++ch) {
            const float a = ws[CMAX_OFF + (size_t)c * 16 + ch];
            const float m = ws[CMIN_OFF + (size_t)c * 16 + ch];
            mm += a; mnm += m; s += ws[CSUM_OFF + (size_t)c * 16 + ch];
            cmx = fmaxf(cmx, a); cmn = fminf(cmn, m);
        }
        mm *= (1.f / 16.f); mnm *= (1.f / 16.f);
        const float mean = s / 50176.f;
        const double PI_D = 3.14159265358979323846;
        const double sfd = 0.175 * (1.0 + sqrt(PI_D * log(4.0))) / sqrt(2.0 * log(3136.0));
        const float scale = 1.f / ((mm - mnm) * (float)sfd + 1e-5f);
        const float A  = scale * ws[QRW_OFF + c];
        const float Bc = ws[QRB_OFF + c] - mean * A;
        ws[A2_OFF + c] = A; ws[B2_OFF + c] = Bc;
        const float v1 = A * cmn + Bc, v2 = A * cmx + Bc;
        lo = fmaxf(0.f, fminf(v1, v2));
        hi = fmaxf(0.f, fmaxf(v1, v2));
    }
    ra[tid] = lo; rb[tid] = hi;
    __syncthreads();
    for (int off = 128; off > 0; off >>= 1) {
        if (tid < off) { ra[tid] = fminf(ra[tid], ra[tid + off]); rb[tid] = fmaxf(rb[tid], rb[tid + off]); }
        __syncthreads();
    }
    if (tid == 0) {
        const float mn3 = ra[0], mx3 = rb[0];
        const float sc = fmaxf((mx3 - mn3) / 255.f, 1e-8f);
        ws[SCAL_OFF + 3] = mn3; ws[SCAL_OFF + 4] = sc; ws[SCAL_OFF + 5] = 1.f / sc; ws[SCAL_OFF + 7] = mx3;
    }
}

// ---------- K5: 3x3 conv fp32, RBN+ReLU+quant fused in staging, writes out[:, 512:544] ----------
__global__ __launch_bounds__(256, 2) void k_conv2(float* __restrict__ out, const float* __restrict__ ws) {
    __shared__ __align__(16) float win[8 * 32 * 12];   // [ci][co][12]
    __shared__ __align__(16) float inb[8 * 12 * 32];   // [ci][row][32], XOR-swizzled cols
    const int tid = threadIdx.x;
    const int qg = blockIdx.x, b = blockIdx.y;
    const int co = tid & 31, q = tid >> 5;
    int gq = qg * 8 + q;
    const bool valid = gq < 49;
    if (!valid) gq = 48;
    const int qy = gq / 7, qx = gq % 7;
    const int y0 = qy * 4, x0 = qx * 4;
    const int ylo = ((qg * 8) / 7) * 4;
    const int r0 = y0 - ylo;
    const float mn3 = ws[SCAL_OFF + 3], sc3 = ws[SCAL_OFF + 4];
    const float inv3 = ws[SCAL_OFF + 5], mx3 = ws[SCAL_OFF + 7];
    float acc[4][4];
#pragma unroll
    for (int i = 0; i < 4; ++i)
#pragma unroll
        for (int j = 0; j < 4; ++j) acc[i][j] = 0.f;

    for (int cc = 0; cc < 16; ++cc) {
        const int ci0 = cc * 8;
        __syncthreads();
        for (int i = tid; i < 768; i += 256)
            ((float4*)win)[i] = ((const float4*)(ws + QW2_OFF + (size_t)ci0 * 384))[i];
        if (tid < 96) {
            const int ci = tid / 12, rr = tid % 12;
            const int r = ylo + rr;
            float* dst = inb + (ci * 12 + rr) * 32;
            if (r <= 29) {
                if (r == 0 || r == 29) {
#pragma unroll
                    for (int cj = 0; cj < 32; ++cj) dst[swz(cj, rr)] = 0.f;
                } else {
                    const float A = ws[A2_OFF + ci0 + ci], Bc = ws[B2_OFF + ci0 + ci];
                    const float* src = ws + H2_OFF + ((size_t)b * C_MID + ci0 + ci) * HW + (r - 1) * 28;
                    dst[swz(0, rr)]  = 0.f;
                    dst[swz(29, rr)] = 0.f; dst[swz(30, rr)] = 0.f; dst[swz(31, rr)] = 0.f;
#pragma unroll
                    for (int j = 0; j < 7; ++j) {
                        const float4 v = ((const float4*)src)[j];
                        dst[swz(1 + j * 4 + 0, rr)] = qact(fmaxf(0.f, fmaf(v.x, A, Bc)), mn3, mx3, inv3, sc3);
                        dst[swz(1 + j * 4 + 1, rr)] = qact(fmaxf(0.f, fmaf(v.y, A, Bc)), mn3, mx3, inv3, sc3);
                        dst[swz(1 + j * 4 + 2, rr)] = qact(fmaxf(0.f, fmaf(v.z, A, Bc)), mn3, mx3, inv3, sc3);
                        dst[swz(1 + j * 4 + 3, rr)] = qact(fmaxf(0.f, fmaf(v.w, A, Bc)), mn3, mx3, inv3, sc3);
                    }
                }
            }
        }
        __syncthreads();
#pragma unroll
        for (int ci = 0; ci < 8; ++ci) {
            const float* wp = win + ((size_t)ci * 32 + co) * 12;
            const float4 w0 = *((const float4*)wp);
            const float4 w1 = *((const float4*)(wp + 4));
            const float  w8 = wp[8];
            const float w9[9] = {w0.x, w0.y, w0.z, w0.w, w1.x, w1.y, w1.z, w1.w, w8};
            float f[6][8];
#pragma unroll
            for (int rr2 = 0; rr2 < 6; ++rr2) {
                const int rl = r0 + rr2;
                const float* rowp = inb + (ci * 12 + rl) * 32;
                const float4 va = *((const float4*)(rowp + ((qx ^ (rl & 7)) << 2)));
                const float4 vb = *((const float4*)(rowp + (((qx + 1) ^ (rl & 7)) << 2)));
                f[rr2][0] = va.x; f[rr2][1] = va.y; f[rr2][2] = va.z; f[rr2][3] = va.w;
                f[rr2][4] = vb.x; f[rr2][5] = vb.y; f[rr2][6] = vb.z; f[rr2][7] = vb.w;
            }
#pragma unroll
            for (int ty = 0; ty < 4; ++ty)
#pragma unroll
                for (int dy = 0; dy < 3; ++dy)
#pragma unroll
                    for (int dx = 0; dx < 3; ++dx) {
                        const float wv = w9[dy * 3 + dx];
#pragma unroll
                        for (int tx = 0; tx < 4; ++tx)
                            acc[ty][tx] = fmaf(wv, f[ty + dy][tx + dx], acc[ty][tx]);
                    }
        }
    }
    if (valid) {
#pragma unroll
        for (int ty = 0; ty < 4; ++ty) {
            float* dst = out + ((size_t)b * C_TOT + 512 + co) * HW + (y0 + ty) * 28 + x0;
            *((float4*)dst) = make_float4(acc[ty][0], acc[ty][1], acc[ty][2], acc[ty][3]);
        }
    }
}

extern "C" void kernel_launch(void* const* d_in, const int* in_sizes, int n_in,
                              void* d_out, int out_size, void* d_ws, size_t ws_size,
                              hipStream_t stream) {
    const float* x       = (const float*)d_in[0];
    const float* bn1_w   = (const float*)d_in[1];
    const float* bn1_b   = (const float*)d_in[2];
    const float* conv1_w = (const float*)d_in[3];
    const float* rbn_w   = (const float*)d_in[4];
    const float* rbn_b   = (const float*)d_in[5];
    const float* conv2_w = (const float*)d_in[6];
    float* out = (float*)d_out;
    float* ws  = (float*)d_ws;

    k_stats_copy<<<dim3(512, 8), 256, 0, stream>>>(x, out, ws);
    k_prep_red<<<44, 256, 0, stream>>>(conv1_w, conv2_w, bn1_w, bn1_b, ws);
    k_prep_fin<<<1, 256, 0, stream>>>(rbn_w, rbn_b, ws);
    k_prep_quant<<<40, 256, 0, stream>>>(conv1_w, conv2_w, ws);
    k_conv1<<<dim3(7, 64), 256, 0, stream>>>(x, ws);
    k_rbn_stats<<<dim3(128, 16), 256, 0, stream>>>(ws);
    k_prep2<<<1, 256, 0, stream>>>(ws);
    k_conv2<<<dim3(7, 64), 256, 0, stream>>>(out, ws);
}

// Round 4
// 111.663 us; speedup vs baseline: 2.9391x; 1.5324x over previous
//
#include <hip/hip_runtime.h>
#include <math.h>

// Dims: x[64,512,28,28] -> out[64,544,28,28] fp32
static constexpr int BB    = 64;
static constexpr int C_IN  = 512;
static constexpr int C_MID = 128;
static constexpr int C_OUT = 32;
static constexpr int C_TOT = 544;
static constexpr int HW    = 784;   // 28*28

// ---- workspace layout (float offsets) ----
static constexpr size_t H2_OFF    = 0;                         // 64*128*784 = 6,422,528
static constexpr size_t QW1_OFF   = 6422528;                   // bf16 [8][128][64] swizzled
static constexpr size_t QW2_OFF   = QW1_OFF + 65536;           // bf16 [co32][k1152] = 18432 floats
static constexpr size_t PSTAT_OFF = QW2_OFF + 49152;           // [512][8][4]
static constexpr size_t BNA_OFF   = PSTAT_OFF + 16384;         // 512
static constexpr size_t BNB_OFF   = BNA_OFF + 512;             // 512
static constexpr size_t CMAX_OFF  = BNB_OFF + 512;             // 128*16
static constexpr size_t CMIN_OFF  = CMAX_OFF + 2048;
static constexpr size_t CSUM_OFF  = CMIN_OFF + 2048;
static constexpr size_t A2_OFF    = CSUM_OFF + 2048;           // 128
static constexpr size_t B2_OFF    = A2_OFF + 128;
static constexpr size_t QRW_OFF   = B2_OFF + 128;
static constexpr size_t QRB_OFF   = QRW_OFF + 128;
static constexpr size_t SCAL_OFF  = QRB_OFF + 128;             // 16 scalars
// SCAL: 0=mn1 1=scale1 2=inv1 3=mn3 4=scale3 5=inv3 6=mx1 7=mx3
//       8=mn_w1 9=sc_w1 10=mn_w2 11=sc_w2
static constexpr size_t PART_OFF  = SCAL_OFF + 16;             // partials

#define DEVFN __device__ __forceinline__

typedef __bf16 bf16x8 __attribute__((ext_vector_type(8)));
typedef float  f32x4  __attribute__((ext_vector_type(4)));

DEVFN float qact(float v, float mn, float mx, float inv, float sc) {
    v = fminf(fmaxf(v, mn), mx);
    return fmaf(rintf((v - mn) * inv), sc, mn);   // rintf == round-half-even == jnp.round
}

DEVFN unsigned f2bf(float f) {                    // fp32 -> bf16 bits, RNE
    unsigned u = __float_as_uint(f);
    return (u + 0x7fffu + ((u >> 16) & 1u)) >> 16;
}

// ---------- K0: per-channel x stats (8 image-groups) + concat copy out[:, :512] = x ----------
__global__ __launch_bounds__(256) void k_stats_copy(const float* __restrict__ x,
                                                    float* __restrict__ out,
                                                    float* __restrict__ ws) {
    const int c = blockIdx.x, bg = blockIdx.y, tid = threadIdx.x;
    float s = 0.f, s2 = 0.f, mn = INFINITY, mx = -INFINITY;
    for (int i = tid; i < 8 * 196; i += 256) {
        const int b = bg * 8 + i / 196, j = i % 196;
        const float4 v = ((const float4*)(x + ((size_t)b * C_IN + c) * HW))[j];
        ((float4*)(out + ((size_t)b * C_TOT + c) * HW))[j] = v;
        s  += (v.x + v.y) + (v.z + v.w);
        s2 += v.x * v.x + v.y * v.y + v.z * v.z + v.w * v.w;
        mn = fminf(mn, fminf(fminf(v.x, v.y), fminf(v.z, v.w)));
        mx = fmaxf(mx, fmaxf(fmaxf(v.x, v.y), fmaxf(v.z, v.w)));
    }
    __shared__ float r0[256], r1[256], r2[256], r3[256];
    r0[tid] = s; r1[tid] = s2; r2[tid] = mn; r3[tid] = mx;
    __syncthreads();
    for (int off = 128; off > 0; off >>= 1) {
        if (tid < off) {
            r0[tid] += r0[tid + off];
            r1[tid] += r1[tid + off];
            r2[tid] = fminf(r2[tid], r2[tid + off]);
            r3[tid] = fmaxf(r3[tid], r3[tid + off]);
        }
        __syncthreads();
    }
    if (tid == 0) {
        float* p = ws + PSTAT_OFF + ((size_t)c * 8 + bg) * 4;
        p[0] = r0[0]; p[1] = r1[0]; p[2] = r2[0]; p[3] = r3[0];
    }
}

// ---------- K1a: parallel reductions — conv1_w/conv2_w min-max partials + BN phase A ----------
__global__ __launch_bounds__(256) void k_prep_red(const float* __restrict__ conv1_w,
                                                  const float* __restrict__ conv2_w,
                                                  const float* __restrict__ bn1_w,
                                                  const float* __restrict__ bn1_b,
                                                  float* __restrict__ ws) {
    const int b = blockIdx.x, tid = threadIdx.x;
    __shared__ float ra[256], rb[256];
    float mn = INFINITY, mx = -INFINITY;

    if (b < 32) {
        const float4* src = (const float4*)conv1_w + (size_t)b * 512;
        for (int i = tid; i < 512; i += 256) {
            const float4 v = src[i];
            mn = fminf(mn, fminf(fminf(v.x, v.y), fminf(v.z, v.w)));
            mx = fmaxf(mx, fmaxf(fmaxf(v.x, v.y), fmaxf(v.z, v.w)));
        }
    } else if (b < 40) {
        const float4* src = (const float4*)conv2_w + (size_t)(b - 32) * 1152;
        for (int i = tid; i < 1152; i += 256) {
            const float4 v = src[i];
            mn = fminf(mn, fminf(fminf(v.x, v.y), fminf(v.z, v.w)));
            mx = fmaxf(mx, fmaxf(fmaxf(v.x, v.y), fmaxf(v.z, v.w)));
        }
    } else {
        if (tid < 128) {
            const int c = (b - 40) * 128 + tid;
            const float* p = ws + PSTAT_OFF + (size_t)c * 32;
            float s = 0.f, s2 = 0.f, cmn = INFINITY, cmx = -INFINITY;
            for (int g = 0; g < 8; ++g) {
                s += p[g * 4 + 0]; s2 += p[g * 4 + 1];
                cmn = fminf(cmn, p[g * 4 + 2]); cmx = fmaxf(cmx, p[g * 4 + 3]);
            }
            const float n = 50176.f;
            const float mean = s / n;
            const float var  = s2 / n - mean * mean;
            const float rstd = rsqrtf(var + 1e-5f);
            const float A  = rstd * bn1_w[c];
            const float Bc = bn1_b[c] - mean * A;
            ws[BNA_OFF + c] = A; ws[BNB_OFF + c] = Bc;
            const float v1 = A * cmn + Bc, v2 = A * cmx + Bc;
            mn = fmaxf(0.f, fminf(v1, v2));
            mx = fmaxf(0.f, fmaxf(v1, v2));
        }
    }
    ra[tid] = mn; rb[tid] = mx;
    __syncthreads();
    for (int off = 128; off > 0; off >>= 1) {
        if (tid < off) { ra[tid] = fminf(ra[tid], ra[tid + off]); rb[tid] = fmaxf(rb[tid], rb[tid + off]); }
        __syncthreads();
    }
    if (tid == 0) {
        float* p;
        if (b < 32)       p = ws + PART_OFF + (size_t)b * 2;
        else if (b < 40)  p = ws + PART_OFF + 64 + (size_t)(b - 32) * 2;
        else              p = ws + PART_OFF + 80 + (size_t)(b - 40) * 2;
        p[0] = ra[0]; p[1] = rb[0];
    }
}

// ---------- K1b: finalize scales + quantize rbn params ----------
__global__ __launch_bounds__(256) void k_prep_fin(const float* __restrict__ rbn_w,
                                                  const float* __restrict__ rbn_b,
                                                  float* __restrict__ ws) {
    const int tid = threadIdx.x;
    __shared__ float ra[256], rb[256];
    __shared__ float s_mn, s_sc;

    ra[tid] = tid < 32 ? ws[PART_OFF + tid * 2] : INFINITY;
    rb[tid] = tid < 32 ? ws[PART_OFF + tid * 2 + 1] : -INFINITY;
    __syncthreads();
    for (int off = 128; off > 0; off >>= 1) {
        if (tid < off) { ra[tid] = fminf(ra[tid], ra[tid + off]); rb[tid] = fmaxf(rb[tid], rb[tid + off]); }
        __syncthreads();
    }
    if (tid == 0) {
        ws[SCAL_OFF + 8] = ra[0];
        ws[SCAL_OFF + 9] = fmaxf((rb[0] - ra[0]) / 255.f, 1e-8f);
    }
    __syncthreads();

    ra[tid] = tid < 8 ? ws[PART_OFF + 64 + tid * 2] : INFINITY;
    rb[tid] = tid < 8 ? ws[PART_OFF + 64 + tid * 2 + 1] : -INFINITY;
    __syncthreads();
    for (int off = 128; off > 0; off >>= 1) {
        if (tid < off) { ra[tid] = fminf(ra[tid], ra[tid + off]); rb[tid] = fmaxf(rb[tid], rb[tid + off]); }
        __syncthreads();
    }
    if (tid == 0) {
        ws[SCAL_OFF + 10] = ra[0];
        ws[SCAL_OFF + 11] = fmaxf((rb[0] - ra[0]) / 255.f, 1e-8f);
    }
    __syncthreads();

    ra[tid] = tid < 4 ? ws[PART_OFF + 80 + tid * 2] : INFINITY;
    rb[tid] = tid < 4 ? ws[PART_OFF + 80 + tid * 2 + 1] : -INFINITY;
    __syncthreads();
    for (int off = 128; off > 0; off >>= 1) {
        if (tid < off) { ra[tid] = fminf(ra[tid], ra[tid + off]); rb[tid] = fmaxf(rb[tid], rb[tid + off]); }
        __syncthreads();
    }
    if (tid == 0) {
        const float mn1 = ra[0], mx1 = rb[0];
        const float sc = fmaxf((mx1 - mn1) / 255.f, 1e-8f);
        ws[SCAL_OFF + 0] = mn1; ws[SCAL_OFF + 1] = sc; ws[SCAL_OFF + 2] = 1.f / sc; ws[SCAL_OFF + 6] = mx1;
    }
    __syncthreads();

    for (int which = 0; which < 2; ++which) {
        const float* src = which ? rbn_b : rbn_w;
        const size_t dst = which ? QRB_OFF : QRW_OFF;
        float v = 0.f;
        ra[tid] = INFINITY; rb[tid] = -INFINITY;
        if (tid < 128) { v = src[tid]; ra[tid] = v; rb[tid] = v; }
        __syncthreads();
        for (int off = 128; off > 0; off >>= 1) {
            if (tid < off) { ra[tid] = fminf(ra[tid], ra[tid + off]); rb[tid] = fmaxf(rb[tid], rb[tid + off]); }
            __syncthreads();
        }
        if (tid == 0) { s_mn = ra[0]; s_sc = fmaxf((rb[0] - ra[0]) / 255.f, 1e-8f); }
        __syncthreads();
        if (tid < 128) ws[dst + tid] = fmaf(rintf((v - s_mn) / s_sc), s_sc, s_mn);
        __syncthreads();
    }
}

// ---------- K1c: parallel weight quantize ----------
__global__ __launch_bounds__(256) void k_prep_quant(const float* __restrict__ conv1_w,
                                                    const float* __restrict__ conv2_w,
                                                    float* __restrict__ ws) {
    const int b = blockIdx.x, tid = threadIdx.x;
    if (b < 32) {                                  // conv1_w -> bf16 swizzled [ks][co][k64]
        const float mnw = ws[SCAL_OFF + 8], scw = ws[SCAL_OFF + 9];
        unsigned short* qw = (unsigned short*)(ws + QW1_OFF);
        const int base = b * 2048;
#pragma unroll
        for (int t = 0; t < 8; ++t) {
            const int i = base + t * 256 + tid;
            const int co = i >> 9, k = i & 511;
            const float v = conv1_w[i];
            const float qv = fmaf(rintf((v - mnw) / scw), scw, mnw);
            const int ks = k >> 6, kc = (k >> 3) & 7, klo = k & 7;
            qw[(((size_t)ks * 128 + co) << 6) + (((kc ^ (co & 7)) << 3) | klo)] = (unsigned short)f2bf(qv);
        }
    } else {                                       // conv2_w -> bf16 [co][k = tap*128 + ci]
        const float mnw = ws[SCAL_OFF + 10], scw = ws[SCAL_OFF + 11];
        unsigned short* qw2 = (unsigned short*)(ws + QW2_OFF);
        const int base = (b - 32) * 4608;
        for (int i2 = tid; i2 < 4608; i2 += 256) {
            const int i = base + i2;
            const int co = i / 1152, r = i % 1152, ci = r / 9, tap = r % 9;
            const float v = conv2_w[i];
            const float qv = fmaf(rintf((v - mnw) / scw), scw, mnw);
            qw2[(size_t)co * 1152 + tap * 128 + ci] = (unsigned short)f2bf(qv);
        }
    }
}

// ---------- K2: 1x1 conv as bf16 MFMA GEMM. M=128co, N=112p, K=512 ----------
__global__ __launch_bounds__(256, 2) void k_conv1(const float* __restrict__ x, float* __restrict__ ws) {
    __shared__ __align__(16) unsigned short wt[128 * 64];
    __shared__ __align__(16) unsigned short ht[112 * 64];
    const int tid = threadIdx.x;
    const int pt = blockIdx.x, b = blockIdx.y;
    const int p0 = pt * 112;
    const float mn1 = ws[SCAL_OFF + 0], sc1 = ws[SCAL_OFF + 1];
    const float inv1 = ws[SCAL_OFF + 2], mx1 = ws[SCAL_OFF + 6];
    const unsigned short* qw1 = (const unsigned short*)(ws + QW1_OFF);
    const float* xb = x + (size_t)b * C_IN * HW;

    const int o = tid & 7, q = tid >> 3;
    const int wv = tid >> 6, g = (tid >> 4) & 3, r4 = tid & 15;

    f32x4 acc[2][7];
#pragma unroll
    for (int i = 0; i < 2; ++i)
#pragma unroll
        for (int j = 0; j < 7; ++j) acc[i][j] = f32x4{0.f, 0.f, 0.f, 0.f};

    for (int ks = 0; ks < 8; ++ks) {
        const float4* wsrc = (const float4*)(qw1 + (size_t)ks * 8192);
        float4* wdst = (float4*)wt;
#pragma unroll
        for (int i = 0; i < 4; ++i) wdst[tid + i * 256] = wsrc[tid + i * 256];

        if (tid < 224) {
            const int ci0 = ks * 64 + o * 8;
            float vv[8][4];
#pragma unroll
            for (int j = 0; j < 8; ++j) {
                const float4 v = *(const float4*)(xb + (size_t)(ci0 + j) * HW + p0 + q * 4);
                const float A = ws[BNA_OFF + ci0 + j], Bc = ws[BNB_OFF + ci0 + j];
                vv[j][0] = qact(fmaxf(0.f, fmaf(v.x, A, Bc)), mn1, mx1, inv1, sc1);
                vv[j][1] = qact(fmaxf(0.f, fmaf(v.y, A, Bc)), mn1, mx1, inv1, sc1);
                vv[j][2] = qact(fmaxf(0.f, fmaf(v.z, A, Bc)), mn1, mx1, inv1, sc1);
                vv[j][3] = qact(fmaxf(0.f, fmaf(v.w, A, Bc)), mn1, mx1, inv1, sc1);
            }
#pragma unroll
            for (int r = 0; r < 4; ++r) {
                const int p = q * 4 + r;
                uint4 pk;
                pk.x = f2bf(vv[0][r]) | (f2bf(vv[1][r]) << 16);
                pk.y = f2bf(vv[2][r]) | (f2bf(vv[3][r]) << 16);
                pk.z = f2bf(vv[4][r]) | (f2bf(vv[5][r]) << 16);
                pk.w = f2bf(vv[6][r]) | (f2bf(vv[7][r]) << 16);
                *(uint4*)&ht[p * 64 + ((o ^ (p & 7)) << 3)] = pk;
            }
        }
        __syncthreads();

#pragma unroll
        for (int ksub = 0; ksub < 2; ++ksub) {
            const int kk = ksub * 4 + g;
            bf16x8 af[2], bfr[7];
#pragma unroll
            for (int ct = 0; ct < 2; ++ct) {
                const int co = wv * 32 + ct * 16 + r4;
                af[ct] = *(const bf16x8*)&wt[co * 64 + ((kk ^ (co & 7)) << 3)];
            }
#pragma unroll
            for (int pf = 0; pf < 7; ++pf) {
                const int p = pf * 16 + r4;
                bfr[pf] = *(const bf16x8*)&ht[p * 64 + ((kk ^ (p & 7)) << 3)];
            }
#pragma unroll
            for (int ct = 0; ct < 2; ++ct)
#pragma unroll
                for (int pf = 0; pf < 7; ++pf)
                    acc[ct][pf] = __builtin_amdgcn_mfma_f32_16x16x32_bf16(af[ct], bfr[pf], acc[ct][pf], 0, 0, 0);
        }
        __syncthreads();
    }

    float* hb = ws + H2_OFF + (size_t)b * C_MID * HW;
#pragma unroll
    for (int ct = 0; ct < 2; ++ct) {
        const int co0 = wv * 32 + ct * 16 + g * 4;
#pragma unroll
        for (int pf = 0; pf < 7; ++pf) {
            const int p = p0 + pf * 16 + r4;
#pragma unroll
            for (int r = 0; r < 4; ++r)
                hb[(size_t)(co0 + r) * HW + p] = acc[ct][pf][r];
        }
    }
}

// ---------- K3: RangeBN chunked stats ----------
__global__ __launch_bounds__(256) void k_rbn_stats(float* __restrict__ ws) {
    const int c = blockIdx.x, ch = blockIdx.y, tid = threadIdx.x;
    float s = 0.f, mn = INFINITY, mx = -INFINITY;
    for (int i = tid; i < 784; i += 256) {
        const int b = ch * 4 + i / 196, j = i % 196;
        const float4 v = ((const float4*)(ws + H2_OFF + ((size_t)b * C_MID + c) * HW))[j];
        s += (v.x + v.y) + (v.z + v.w);
        mn = fminf(mn, fminf(fminf(v.x, v.y), fminf(v.z, v.w)));
        mx = fmaxf(mx, fmaxf(fmaxf(v.x, v.y), fmaxf(v.z, v.w)));
    }
    __shared__ float r0[256], r1[256], r2[256];
    r0[tid] = s; r1[tid] = mn; r2[tid] = mx;
    __syncthreads();
    for (int off = 128; off > 0; off >>= 1) {
        if (tid < off) {
            r0[tid] += r0[tid + off];
            r1[tid] = fminf(r1[tid], r1[tid + off]);
            r2[tid] = fmaxf(r2[tid], r2[tid + off]);
        }
        __syncthreads();
    }
    if (tid == 0) {
        ws[CSUM_OFF + (size_t)c * 16 + ch] = r0[0];
        ws[CMIN_OFF + (size_t)c * 16 + ch] = r1[0];
        ws[CMAX_OFF + (size_t)c * 16 + ch] = r2[0];
    }
}

// ---------- K4: RangeBN affine + h3 range ----------
__global__ __launch_bounds__(256) void k_prep2(float* __restrict__ ws) {
    const int tid = threadIdx.x;
    __shared__ float ra[256], rb[256];
    float lo = INFINITY, hi = -INFINITY;
    if (tid < 128) {
        const int c = tid;
        float mm = 0.f, mnm = 0.f, s = 0.f, cmx = -INFINITY, cmn = INFINITY;
        for (int ch = 0; ch < 16; ++ch) {
            const float a = ws[CMAX_OFF + (size_t)c * 16 + ch];
            const float m = ws[CMIN_OFF + (size_t)c * 16 + ch];
            mm += a; mnm += m; s += ws[CSUM_OFF + (size_t)c * 16 + ch];
            cmx = fmaxf(cmx, a); cmn = fminf(cmn, m);
        }
        mm *= (1.f / 16.f); mnm *= (1.f / 16.f);
        const float mean = s / 50176.f;
        const double PI_D = 3.14159265358979323846;
        const double sfd = 0.175 * (1.0 + sqrt(PI_D * log(4.0))) / sqrt(2.0 * log(3136.0));
        const float scale = 1.f / ((mm - mnm) * (float)sfd + 1e-5f);
        const float A  = scale * ws[QRW_OFF + c];
        const float Bc = ws[QRB_OFF + c] - mean * A;
        ws[A2_OFF + c] = A; ws[B2_OFF + c] = Bc;
        const float v1 = A * cmn + Bc, v2 = A * cmx + Bc;
        lo = fmaxf(0.f, fminf(v1, v2));
        hi = fmaxf(0.f, fmaxf(v1, v2));
    }
    ra[tid] = lo; rb[tid] = hi;
    __syncthreads();
    for (int off = 128; off > 0; off >>= 1) {
        if (tid < off) { ra[tid] = fminf(ra[tid], ra[tid + off]); rb[tid] = fmaxf(rb[tid], rb[tid + off]); }
        __syncthreads();
    }
    if (tid == 0) {
        const float mn3 = ra[0], mx3 = rb[0];
        const float sc = fmaxf((mx3 - mn3) / 255.f, 1e-8f);
        ws[SCAL_OFF + 3] = mn3; ws[SCAL_OFF + 4] = sc; ws[SCAL_OFF + 5] = 1.f / sc; ws[SCAL_OFF + 7] = mx3;
    }
}

// ---------- K5: 3x3 conv via MFMA implicit im2col. M=32co, K=1152, N=112 px/block ----------
__global__ __launch_bounds__(128) void k_conv2(float* __restrict__ out, const float* __restrict__ ws) {
    // padded act tile: [row 0..6][col 0..29][phys_oct 0..15][8 ci] bf16, phys=(oct+col)&15
    __shared__ __align__(16) unsigned short lact[7 * 30 * 128];   // 53,760 B
    const int tid = threadIdx.x;
    const int pt = blockIdx.x, b = blockIdx.y;
    const int y0 = pt * 4;
    const float mn3 = ws[SCAL_OFF + 3], sc3 = ws[SCAL_OFF + 4];
    const float inv3 = ws[SCAL_OFF + 5], mx3 = ws[SCAL_OFF + 7];

    {   // zero-fill (borders + pad row stay zero)
        const uint4 z = {0u, 0u, 0u, 0u};
        uint4* lp = (uint4*)lact;
        for (int i = tid; i < 3360; i += 128) lp[i] = z;
    }
    __syncthreads();

    // stage interior rows with fused RBN+ReLU+quant+bf16; tasks = (oct16, r6, xq7)
    const float* h2b = ws + H2_OFF + (size_t)b * C_MID * HW;
    for (int task = tid; task < 672; task += 128) {
        const int oct = task / 42, rem = task % 42, r = rem / 7, xq = rem % 7;
        const int gy = y0 - 1 + r;
        if (gy < 0 || gy > 27) continue;
        float vv[8][4];
#pragma unroll
        for (int j = 0; j < 8; ++j) {
            const int ci = oct * 8 + j;
            const float4 v = *(const float4*)(h2b + (size_t)ci * HW + gy * 28 + xq * 4);
            const float A = ws[A2_OFF + ci], Bc = ws[B2_OFF + ci];
            vv[j][0] = qact(fmaxf(0.f, fmaf(v.x, A, Bc)), mn3, mx3, inv3, sc3);
            vv[j][1] = qact(fmaxf(0.f, fmaf(v.y, A, Bc)), mn3, mx3, inv3, sc3);
            vv[j][2] = qact(fmaxf(0.f, fmaf(v.z, A, Bc)), mn3, mx3, inv3, sc3);
            vv[j][3] = qact(fmaxf(0.f, fmaf(v.w, A, Bc)), mn3, mx3, inv3, sc3);
        }
#pragma unroll
        for (int xi = 0; xi < 4; ++xi) {
            const int col = xq * 4 + xi + 1;          // staged col c holds global x = c-1
            const int phys = (oct + col) & 15;
            uint4 pk;
            pk.x = f2bf(vv[0][xi]) | (f2bf(vv[1][xi]) << 16);
            pk.y = f2bf(vv[2][xi]) | (f2bf(vv[3][xi]) << 16);
            pk.z = f2bf(vv[4][xi]) | (f2bf(vv[5][xi]) << 16);
            pk.w = f2bf(vv[6][xi]) | (f2bf(vv[7][xi]) << 16);
            *(uint4*)&lact[((r * 30 + col) * 16 + phys) * 8] = pk;
        }
    }
    __syncthreads();

    // compute: wave wv handles p-frags wv*4 .. wv*4+3 (pf 7 is padded garbage, discarded)
    const int wv = tid >> 6, lane = tid & 63, r4 = lane & 15, g = lane >> 4;
    int py[4], px[4];
#pragma unroll
    for (int i = 0; i < 4; ++i) {
        const int p = (wv * 4 + i) * 16 + r4;
        py[i] = p / 28; px[i] = p % 28;
    }
    f32x4 acc[2][4];
#pragma unroll
    for (int ct = 0; ct < 2; ++ct)
#pragma unroll
        for (int i = 0; i < 4; ++i) acc[ct][i] = f32x4{0.f, 0.f, 0.f, 0.f};

    const unsigned short* qw2 = (const unsigned short*)(ws + QW2_OFF);
    for (int tap = 0; tap < 9; ++tap) {
        const int dy = tap / 3, dx = tap % 3;
        bf16x8 afr[2][4];
#pragma unroll
        for (int ct = 0; ct < 2; ++ct)
#pragma unroll
            for (int c4 = 0; c4 < 4; ++c4) {
                const int co = ct * 16 + r4;
                afr[ct][c4] = *(const bf16x8*)&qw2[(size_t)co * 1152 + tap * 128 + c4 * 32 + g * 8];
            }
#pragma unroll
        for (int c4 = 0; c4 < 4; ++c4) {
            bf16x8 bfr[4];
#pragma unroll
            for (int i = 0; i < 4; ++i) {
                const int row = py[i] + dy, col = px[i] + dx;
                const int phys = (c4 * 4 + g + col) & 15;
                bfr[i] = *(const bf16x8*)&lact[((row * 30 + col) * 16 + phys) * 8];
            }
#pragma unroll
            for (int ct = 0; ct < 2; ++ct)
#pragma unroll
                for (int i = 0; i < 4; ++i)
                    acc[ct][i] = __builtin_amdgcn_mfma_f32_16x16x32_bf16(afr[ct][c4], bfr[i], acc[ct][i], 0, 0, 0);
        }
    }

    // epilogue: C row = g*4+reg (co within frag), col = r4 (p within frag)
#pragma unroll
    for (int ct = 0; ct < 2; ++ct)
#pragma unroll
        for (int i = 0; i < 4; ++i) {
            const int pf = wv * 4 + i;
            if (pf < 7) {
                const int p = pf * 16 + r4;
#pragma unroll
                for (int r = 0; r < 4; ++r) {
                    const int co = ct * 16 + g * 4 + r;
                    out[((size_t)b * C_TOT + 512 + co) * HW + y0 * 28 + p] = acc[ct][i][r];
                }
            }
        }
}

extern "C" void kernel_launch(void* const* d_in, const int* in_sizes, int n_in,
                              void* d_out, int out_size, void* d_ws, size_t ws_size,
                              hipStream_t stream) {
    const float* x       = (const float*)d_in[0];
    const float* bn1_w   = (const float*)d_in[1];
    const float* bn1_b   = (const float*)d_in[2];
    const float* conv1_w = (const float*)d_in[3];
    const float* rbn_w   = (const float*)d_in[4];
    const float* rbn_b   = (const float*)d_in[5];
    const float* conv2_w = (const float*)d_in[6];
    float* out = (float*)d_out;
    float* ws  = (float*)d_ws;

    k_stats_copy<<<dim3(512, 8), 256, 0, stream>>>(x, out, ws);
    k_prep_red<<<44, 256, 0, stream>>>(conv1_w, conv2_w, bn1_w, bn1_b, ws);
    k_prep_fin<<<1, 256, 0, stream>>>(rbn_w, rbn_b, ws);
    k_prep_quant<<<40, 256, 0, stream>>>(conv1_w, conv2_w, ws);
    k_conv1<<<dim3(7, 64), 256, 0, stream>>>(x, ws);
    k_rbn_stats<<<dim3(128, 16), 256, 0, stream>>>(ws);
    k_prep2<<<1, 256, 0, stream>>>(ws);
    k_conv2<<<dim3(7, 64), 128, 0, stream>>>(out, ws);
}

// Round 6
// 106.112 us; speedup vs baseline: 3.0929x; 1.0523x over previous
//
#include <hip/hip_runtime.h>
#include <math.h>

// Dims: x[64,512,28,28] -> out[64,544,28,28] fp32
static constexpr int BB    = 64;
static constexpr int C_IN  = 512;
static constexpr int C_MID = 128;
static constexpr int C_OUT = 32;
static constexpr int C_TOT = 544;
static constexpr int HW    = 784;   // 28*28

// ---- workspace layout (float offsets). Total ~26.9 MB ----
static constexpr size_t H2_OFF    = 0;                         // 64*128*784 = 6,422,528
static constexpr size_t QW1_OFF   = 6422528;                   // bf16 [8][128][64] swizzled
static constexpr size_t QW2_OFF   = QW1_OFF + 65536;           // bf16 [co32][k1152]
static constexpr size_t PSTAT_OFF = QW2_OFF + 49152;           // [512][8][4]
static constexpr size_t BNA_OFF   = PSTAT_OFF + 16384;         // 512
static constexpr size_t BNB_OFF   = BNA_OFF + 512;             // 512
static constexpr size_t CMAX_OFF  = BNB_OFF + 512;             // (unused, kept for layout)
static constexpr size_t CMIN_OFF  = CMAX_OFF + 2048;
static constexpr size_t CSUM_OFF  = CMIN_OFF + 2048;
static constexpr size_t A2_OFF    = CSUM_OFF + 2048;           // 128
static constexpr size_t B2_OFF    = A2_OFF + 128;
static constexpr size_t QRW_OFF   = B2_OFF + 128;
static constexpr size_t QRB_OFF   = QRW_OFF + 128;
static constexpr size_t SCAL_OFF  = QRB_OFF + 128;             // 16 scalars
// SCAL: 0=mn1 1=scale1 2=inv1 3=mn3 4=scale3 5=inv3 6=mx1 7=mx3
//       8=mn_w1 9=sc_w1 10=mn_w2 11=sc_w2
static constexpr size_t PART_OFF  = SCAL_OFF + 16;             // small partials (128)
static constexpr size_t RP_OFF    = PART_OFF + 128;            // rbn partials [co128][b64][pt7][3]
static constexpr size_t PART2_OFF = RP_OFF + 172032;           // per-channel h3 lo/hi [128][2]

#define DEVFN __device__ __forceinline__

typedef __bf16 bf16x8 __attribute__((ext_vector_type(8)));
typedef float  f32x4  __attribute__((ext_vector_type(4)));

DEVFN float qact(float v, float mn, float mx, float inv, float sc) {
    v = fminf(fmaxf(v, mn), mx);
    return fmaf(rintf((v - mn) * inv), sc, mn);   // rintf == round-half-even == jnp.round
}

DEVFN unsigned f2bf(float f) {                    // fp32 -> bf16 bits, RNE
    unsigned u = __float_as_uint(f);
    return (u + 0x7fffu + ((u >> 16) & 1u)) >> 16;
}

// ---------- K0: per-channel x stats only (read-only; copy moved into conv1) ----------
__global__ __launch_bounds__(256) void k_stats(const float* __restrict__ x,
                                               float* __restrict__ ws) {
    const int c = blockIdx.x, bg = blockIdx.y, tid = threadIdx.x;
    float s = 0.f, s2 = 0.f, mn = INFINITY, mx = -INFINITY;
    if (tid < 224) {                               // 224 threads x 7 unrolled f4 loads = 1568
#pragma unroll
        for (int k = 0; k < 7; ++k) {
            const int idx = k * 224 + tid;
            const int b = bg * 8 + idx / 196, j = idx % 196;
            const float4 v = ((const float4*)(x + ((size_t)b * C_IN + c) * HW))[j];
            s  += (v.x + v.y) + (v.z + v.w);
            s2 += v.x * v.x + v.y * v.y + v.z * v.z + v.w * v.w;
            mn = fminf(mn, fminf(fminf(v.x, v.y), fminf(v.z, v.w)));
            mx = fmaxf(mx, fmaxf(fmaxf(v.x, v.y), fmaxf(v.z, v.w)));
        }
    }
    __shared__ float r0[256], r1[256], r2[256], r3[256];
    r0[tid] = s; r1[tid] = s2; r2[tid] = mn; r3[tid] = mx;
    __syncthreads();
    for (int off = 128; off > 0; off >>= 1) {
        if (tid < off) {
            r0[tid] += r0[tid + off];
            r1[tid] += r1[tid + off];
            r2[tid] = fminf(r2[tid], r2[tid + off]);
            r3[tid] = fmaxf(r3[tid], r3[tid + off]);
        }
        __syncthreads();
    }
    if (tid == 0) {
        float* p = ws + PSTAT_OFF + ((size_t)c * 8 + bg) * 4;
        p[0] = r0[0]; p[1] = r1[0]; p[2] = r2[0]; p[3] = r3[0];
    }
}

// ---------- K1a: parallel reductions — conv1_w/conv2_w min-max partials + BN phase A ----------
__global__ __launch_bounds__(256) void k_prep_red(const float* __restrict__ conv1_w,
                                                  const float* __restrict__ conv2_w,
                                                  const float* __restrict__ bn1_w,
                                                  const float* __restrict__ bn1_b,
                                                  float* __restrict__ ws) {
    const int b = blockIdx.x, tid = threadIdx.x;
    __shared__ float ra[256], rb[256];
    float mn = INFINITY, mx = -INFINITY;

    if (b < 32) {
        const float4* src = (const float4*)conv1_w + (size_t)b * 512;
        for (int i = tid; i < 512; i += 256) {
            const float4 v = src[i];
            mn = fminf(mn, fminf(fminf(v.x, v.y), fminf(v.z, v.w)));
            mx = fmaxf(mx, fmaxf(fmaxf(v.x, v.y), fmaxf(v.z, v.w)));
        }
    } else if (b < 40) {
        const float4* src = (const float4*)conv2_w + (size_t)(b - 32) * 1152;
        for (int i = tid; i < 1152; i += 256) {
            const float4 v = src[i];
            mn = fminf(mn, fminf(fminf(v.x, v.y), fminf(v.z, v.w)));
            mx = fmaxf(mx, fmaxf(fmaxf(v.x, v.y), fmaxf(v.z, v.w)));
        }
    } else {
        if (tid < 128) {
            const int c = (b - 40) * 128 + tid;
            const float* p = ws + PSTAT_OFF + (size_t)c * 32;
            float s = 0.f, s2 = 0.f, cmn = INFINITY, cmx = -INFINITY;
            for (int g = 0; g < 8; ++g) {
                s += p[g * 4 + 0]; s2 += p[g * 4 + 1];
                cmn = fminf(cmn, p[g * 4 + 2]); cmx = fmaxf(cmx, p[g * 4 + 3]);
            }
            const float n = 50176.f;
            const float mean = s / n;
            const float var  = s2 / n - mean * mean;
            const float rstd = rsqrtf(var + 1e-5f);
            const float A  = rstd * bn1_w[c];
            const float Bc = bn1_b[c] - mean * A;
            ws[BNA_OFF + c] = A; ws[BNB_OFF + c] = Bc;
            const float v1 = A * cmn + Bc, v2 = A * cmx + Bc;
            mn = fmaxf(0.f, fminf(v1, v2));
            mx = fmaxf(0.f, fmaxf(v1, v2));
        }
    }
    ra[tid] = mn; rb[tid] = mx;
    __syncthreads();
    for (int off = 128; off > 0; off >>= 1) {
        if (tid < off) { ra[tid] = fminf(ra[tid], ra[tid + off]); rb[tid] = fmaxf(rb[tid], rb[tid + off]); }
        __syncthreads();
    }
    if (tid == 0) {
        float* p;
        if (b < 32)       p = ws + PART_OFF + (size_t)b * 2;
        else if (b < 40)  p = ws + PART_OFF + 64 + (size_t)(b - 32) * 2;
        else              p = ws + PART_OFF + 80 + (size_t)(b - 40) * 2;
        p[0] = ra[0]; p[1] = rb[0];
    }
}

// ---------- K1b: finalize scales + quantize rbn params ----------
__global__ __launch_bounds__(256) void k_prep_fin(const float* __restrict__ rbn_w,
                                                  const float* __restrict__ rbn_b,
                                                  float* __restrict__ ws) {
    const int tid = threadIdx.x;
    __shared__ float ra[256], rb[256];
    __shared__ float s_mn, s_sc;

    ra[tid] = tid < 32 ? ws[PART_OFF + tid * 2] : INFINITY;
    rb[tid] = tid < 32 ? ws[PART_OFF + tid * 2 + 1] : -INFINITY;
    __syncthreads();
    for (int off = 128; off > 0; off >>= 1) {
        if (tid < off) { ra[tid] = fminf(ra[tid], ra[tid + off]); rb[tid] = fmaxf(rb[tid], rb[tid + off]); }
        __syncthreads();
    }
    if (tid == 0) {
        ws[SCAL_OFF + 8] = ra[0];
        ws[SCAL_OFF + 9] = fmaxf((rb[0] - ra[0]) / 255.f, 1e-8f);
    }
    __syncthreads();

    ra[tid] = tid < 8 ? ws[PART_OFF + 64 + tid * 2] : INFINITY;
    rb[tid] = tid < 8 ? ws[PART_OFF + 64 + tid * 2 + 1] : -INFINITY;
    __syncthreads();
    for (int off = 128; off > 0; off >>= 1) {
        if (tid < off) { ra[tid] = fminf(ra[tid], ra[tid + off]); rb[tid] = fmaxf(rb[tid], rb[tid + off]); }
        __syncthreads();
    }
    if (tid == 0) {
        ws[SCAL_OFF + 10] = ra[0];
        ws[SCAL_OFF + 11] = fmaxf((rb[0] - ra[0]) / 255.f, 1e-8f);
    }
    __syncthreads();

    ra[tid] = tid < 4 ? ws[PART_OFF + 80 + tid * 2] : INFINITY;
    rb[tid] = tid < 4 ? ws[PART_OFF + 80 + tid * 2 + 1] : -INFINITY;
    __syncthreads();
    for (int off = 128; off > 0; off >>= 1) {
        if (tid < off) { ra[tid] = fminf(ra[tid], ra[tid + off]); rb[tid] = fmaxf(rb[tid], rb[tid + off]); }
        __syncthreads();
    }
    if (tid == 0) {
        const float mn1 = ra[0], mx1 = rb[0];
        const float sc = fmaxf((mx1 - mn1) / 255.f, 1e-8f);
        ws[SCAL_OFF + 0] = mn1; ws[SCAL_OFF + 1] = sc; ws[SCAL_OFF + 2] = 1.f / sc; ws[SCAL_OFF + 6] = mx1;
    }
    __syncthreads();

    for (int which = 0; which < 2; ++which) {
        const float* src = which ? rbn_b : rbn_w;
        const size_t dst = which ? QRB_OFF : QRW_OFF;
        float v = 0.f;
        ra[tid] = INFINITY; rb[tid] = -INFINITY;
        if (tid < 128) { v = src[tid]; ra[tid] = v; rb[tid] = v; }
        __syncthreads();
        for (int off = 128; off > 0; off >>= 1) {
            if (tid < off) { ra[tid] = fminf(ra[tid], ra[tid + off]); rb[tid] = fmaxf(rb[tid], rb[tid + off]); }
            __syncthreads();
        }
        if (tid == 0) { s_mn = ra[0]; s_sc = fmaxf((rb[0] - ra[0]) / 255.f, 1e-8f); }
        __syncthreads();
        if (tid < 128) ws[dst + tid] = fmaf(rintf((v - s_mn) / s_sc), s_sc, s_mn);
        __syncthreads();
    }
}

// ---------- K1c: parallel weight quantize ----------
__global__ __launch_bounds__(256) void k_prep_quant(const float* __restrict__ conv1_w,
                                                    const float* __restrict__ conv2_w,
                                                    float* __restrict__ ws) {
    const int b = blockIdx.x, tid = threadIdx.x;
    if (b < 32) {                                  // conv1_w -> bf16 swizzled [ks][co][k64]
        const float mnw = ws[SCAL_OFF + 8], scw = ws[SCAL_OFF + 9];
        unsigned short* qw = (unsigned short*)(ws + QW1_OFF);
        const int base = b * 2048;
#pragma unroll
        for (int t = 0; t < 8; ++t) {
            const int i = base + t * 256 + tid;
            const int co = i >> 9, k = i & 511;
            const float v = conv1_w[i];
            const float qv = fmaf(rintf((v - mnw) / scw), scw, mnw);
            const int ks = k >> 6, kc = (k >> 3) & 7, klo = k & 7;
            qw[(((size_t)ks * 128 + co) << 6) + (((kc ^ (co & 7)) << 3) | klo)] = (unsigned short)f2bf(qv);
        }
    } else {                                       // conv2_w -> bf16 [co][k = tap*128 + ci]
        const float mnw = ws[SCAL_OFF + 10], scw = ws[SCAL_OFF + 11];
        unsigned short* qw2 = (unsigned short*)(ws + QW2_OFF);
        const int base = (b - 32) * 4608;
        for (int i2 = tid; i2 < 4608; i2 += 256) {
            const int i = base + i2;
            const int co = i / 1152, r = i % 1152, ci = r / 9, tap = r % 9;
            const float v = conv2_w[i];
            const float qv = fmaf(rintf((v - mnw) / scw), scw, mnw);
            qw2[(size_t)co * 1152 + tap * 128 + ci] = (unsigned short)f2bf(qv);
        }
    }
}

// ---------- K2: 1x1 conv MFMA GEMM + fused concat-copy + fused RBN partial stats ----------
__global__ __launch_bounds__(256, 2) void k_conv1(const float* __restrict__ x,
                                                  float* __restrict__ out,
                                                  float* __restrict__ ws) {
    __shared__ __align__(16) unsigned short wt[128 * 64];
    __shared__ __align__(16) unsigned short ht[112 * 64];
    const int tid = threadIdx.x;
    const int pt = blockIdx.x, b = blockIdx.y;
    const int p0 = pt * 112;
    const float mn1 = ws[SCAL_OFF + 0], sc1 = ws[SCAL_OFF + 1];
    const float inv1 = ws[SCAL_OFF + 2], mx1 = ws[SCAL_OFF + 6];
    const unsigned short* qw1 = (const unsigned short*)(ws + QW1_OFF);
    const float* xb = x + (size_t)b * C_IN * HW;
    float* outb = out + (size_t)b * C_TOT * HW;

    const int o = tid & 7, q = tid >> 3;
    const int wv = tid >> 6, g = (tid >> 4) & 3, r4 = tid & 15;

    f32x4 acc[2][7];
#pragma unroll
    for (int i = 0; i < 2; ++i)
#pragma unroll
        for (int j = 0; j < 7; ++j) acc[i][j] = f32x4{0.f, 0.f, 0.f, 0.f};

    for (int ks = 0; ks < 8; ++ks) {
        const float4* wsrc = (const float4*)(qw1 + (size_t)ks * 8192);
        float4* wdst = (float4*)wt;
#pragma unroll
        for (int i = 0; i < 4; ++i) wdst[tid + i * 256] = wsrc[tid + i * 256];

        if (tid < 224) {
            const int ci0 = ks * 64 + o * 8;
            float vv[8][4];
#pragma unroll
            for (int j = 0; j < 8; ++j) {
                const f32x4 v = *(const f32x4*)(xb + (size_t)(ci0 + j) * HW + p0 + q * 4);
                // fused concat copy: out[:, :512] = x (raw), nontemporal (never re-read)
                __builtin_nontemporal_store(v, (f32x4*)(outb + (size_t)(ci0 + j) * HW + p0 + q * 4));
                const float A = ws[BNA_OFF + ci0 + j], Bc = ws[BNB_OFF + ci0 + j];
                vv[j][0] = qact(fmaxf(0.f, fmaf(v.x, A, Bc)), mn1, mx1, inv1, sc1);
                vv[j][1] = qact(fmaxf(0.f, fmaf(v.y, A, Bc)), mn1, mx1, inv1, sc1);
                vv[j][2] = qact(fmaxf(0.f, fmaf(v.z, A, Bc)), mn1, mx1, inv1, sc1);
                vv[j][3] = qact(fmaxf(0.f, fmaf(v.w, A, Bc)), mn1, mx1, inv1, sc1);
            }
#pragma unroll
            for (int r = 0; r < 4; ++r) {
                const int p = q * 4 + r;
                uint4 pk;
                pk.x = f2bf(vv[0][r]) | (f2bf(vv[1][r]) << 16);
                pk.y = f2bf(vv[2][r]) | (f2bf(vv[3][r]) << 16);
                pk.z = f2bf(vv[4][r]) | (f2bf(vv[5][r]) << 16);
                pk.w = f2bf(vv[6][r]) | (f2bf(vv[7][r]) << 16);
                *(uint4*)&ht[p * 64 + ((o ^ (p & 7)) << 3)] = pk;
            }
        }
        __syncthreads();

#pragma unroll
        for (int ksub = 0; ksub < 2; ++ksub) {
            const int kk = ksub * 4 + g;
            bf16x8 af[2], bfr[7];
#pragma unroll
            for (int ct = 0; ct < 2; ++ct) {
                const int co = wv * 32 + ct * 16 + r4;
                af[ct] = *(const bf16x8*)&wt[co * 64 + ((kk ^ (co & 7)) << 3)];
            }
#pragma unroll
            for (int pf = 0; pf < 7; ++pf) {
                const int p = pf * 16 + r4;
                bfr[pf] = *(const bf16x8*)&ht[p * 64 + ((kk ^ (p & 7)) << 3)];
            }
#pragma unroll
            for (int ct = 0; ct < 2; ++ct)
#pragma unroll
                for (int pf = 0; pf < 7; ++pf)
                    acc[ct][pf] = __builtin_amdgcn_mfma_f32_16x16x32_bf16(af[ct], bfr[pf], acc[ct][pf], 0, 0, 0);
        }
        __syncthreads();
    }

    // write h2
    float* hb = ws + H2_OFF + (size_t)b * C_MID * HW;
#pragma unroll
    for (int ct = 0; ct < 2; ++ct) {
        const int co0 = wv * 32 + ct * 16 + g * 4;
#pragma unroll
        for (int pf = 0; pf < 7; ++pf) {
            const int p = p0 + pf * 16 + r4;
#pragma unroll
            for (int r = 0; r < 4; ++r)
                hb[(size_t)(co0 + r) * HW + p] = acc[ct][pf][r];
        }
    }

    // fused RangeBN per-block partials: for each co this wave owns, reduce {sum,min,max}
    // over its 112 p-values (7 pf in-thread + 16-lane shuffle across r4)
#pragma unroll
    for (int ct = 0; ct < 2; ++ct)
#pragma unroll
        for (int r = 0; r < 4; ++r) {
            float s = 0.f, mn = INFINITY, mx = -INFINITY;
#pragma unroll
            for (int pf = 0; pf < 7; ++pf) {
                const float v = acc[ct][pf][r];
                s += v; mn = fminf(mn, v); mx = fmaxf(mx, v);
            }
#pragma unroll
            for (int m = 1; m < 16; m <<= 1) {
                s  += __shfl_xor(s, m, 64);
                mn  = fminf(mn, __shfl_xor(mn, m, 64));
                mx  = fmaxf(mx, __shfl_xor(mx, m, 64));
            }
            if (r4 == 0) {
                const int co = wv * 32 + ct * 16 + g * 4 + r;
                float* dst = ws + RP_OFF + (((size_t)co * 64 + b) * 7 + pt) * 3;
                dst[0] = s; dst[1] = mn; dst[2] = mx;
            }
        }
}

// ---------- K3: combine RBN partials -> per-channel affine + h3 endpoints ----------
__global__ __launch_bounds__(64) void k_rbn_combine(float* __restrict__ ws) {
    const int c = blockIdx.x, t = threadIdx.x;
    const int ch = t >> 2, sub = t & 3;            // chunk 0..15, sub-image 0..3
    const int b = ch * 4 + sub;
    const float* rp = ws + RP_OFF + ((size_t)c * 64 + b) * 21;
    float s = 0.f, mn = INFINITY, mx = -INFINITY;
#pragma unroll
    for (int pt = 0; pt < 7; ++pt) {
        s += rp[pt * 3 + 0];
        mn = fminf(mn, rp[pt * 3 + 1]);
        mx = fmaxf(mx, rp[pt * 3 + 2]);
    }
#pragma unroll
    for (int m = 1; m < 4; m <<= 1) {              // reduce 4 images -> chunk
        s  += __shfl_xor(s, m, 64);
        mn  = fminf(mn, __shfl_xor(mn, m, 64));
        mx  = fmaxf(mx, __shfl_xor(mx, m, 64));
    }
    // across 16 chunks: sum of chunk-max/min (for means), total sum, global min/max
    float smx = mx, smn = mn, stot = s, gmn = mn, gmx = mx;
#pragma unroll
    for (int m = 4; m < 64; m <<= 1) {
        smx  += __shfl_xor(smx, m, 64);
        smn  += __shfl_xor(smn, m, 64);
        stot += __shfl_xor(stot, m, 64);
        gmn   = fminf(gmn, __shfl_xor(gmn, m, 64));
        gmx   = fmaxf(gmx, __shfl_xor(gmx, m, 64));
    }
    if (t == 0) {
        const float mm = smx * (1.f / 16.f), mnm = smn * (1.f / 16.f);
        const float mean = stot / 50176.f;
        const double PI_D = 3.14159265358979323846;
        const double sfd = 0.175 * (1.0 + sqrt(PI_D * log(4.0))) / sqrt(2.0 * log(3136.0));
        const float scale = 1.f / ((mm - mnm) * (float)sfd + 1e-5f);
        const float A  = scale * ws[QRW_OFF + c];
        const float Bc = ws[QRB_OFF + c] - mean * A;
        ws[A2_OFF + c] = A; ws[B2_OFF + c] = Bc;
        const float v1 = A * gmn + Bc, v2 = A * gmx + Bc;
        ws[PART2_OFF + c * 2 + 0] = fmaxf(0.f, fminf(v1, v2));
        ws[PART2_OFF + c * 2 + 1] = fmaxf(0.f, fmaxf(v1, v2));
    }
}

// ---------- K4: global h3 range (128 channels -> scale) ----------
__global__ __launch_bounds__(64) void k_prep2b(float* __restrict__ ws) {
    const int t = threadIdx.x;
    float lo = fminf(ws[PART2_OFF + t * 2], ws[PART2_OFF + (t + 64) * 2]);
    float hi = fmaxf(ws[PART2_OFF + t * 2 + 1], ws[PART2_OFF + (t + 64) * 2 + 1]);
#pragma unroll
    for (int m = 1; m < 64; m <<= 1) {
        lo = fminf(lo, __shfl_xor(lo, m, 64));
        hi = fmaxf(hi, __shfl_xor(hi, m, 64));
    }
    if (t == 0) {
        const float sc = fmaxf((hi - lo) / 255.f, 1e-8f);
        ws[SCAL_OFF + 3] = lo; ws[SCAL_OFF + 4] = sc; ws[SCAL_OFF + 5] = 1.f / sc; ws[SCAL_OFF + 7] = hi;
    }
}

// ---------- K5: 3x3 conv via MFMA implicit im2col ----------
__global__ __launch_bounds__(128) void k_conv2(float* __restrict__ out, const float* __restrict__ ws) {
    __shared__ __align__(16) unsigned short lact[7 * 30 * 128];
    const int tid = threadIdx.x;
    const int pt = blockIdx.x, b = blockIdx.y;
    const int y0 = pt * 4;
    const float mn3 = ws[SCAL_OFF + 3], sc3 = ws[SCAL_OFF + 4];
    const float inv3 = ws[SCAL_OFF + 5], mx3 = ws[SCAL_OFF + 7];

    {
        const uint4 z = {0u, 0u, 0u, 0u};
        uint4* lp = (uint4*)lact;
        for (int i = tid; i < 3360; i += 128) lp[i] = z;
    }
    __syncthreads();

    const float* h2b = ws + H2_OFF + (size_t)b * C_MID * HW;
    for (int task = tid; task < 672; task += 128) {
        const int oct = task / 42, rem = task % 42, r = rem / 7, xq = rem % 7;
        const int gy = y0 - 1 + r;
        if (gy < 0 || gy > 27) continue;
        float vv[8][4];
#pragma unroll
        for (int j = 0; j < 8; ++j) {
            const int ci = oct * 8 + j;
            const float4 v = *(const float4*)(h2b + (size_t)ci * HW + gy * 28 + xq * 4);
            const float A = ws[A2_OFF + ci], Bc = ws[B2_OFF + ci];
            vv[j][0] = qact(fmaxf(0.f, fmaf(v.x, A, Bc)), mn3, mx3, inv3, sc3);
            vv[j][1] = qact(fmaxf(0.f, fmaf(v.y, A, Bc)), mn3, mx3, inv3, sc3);
            vv[j][2] = qact(fmaxf(0.f, fmaf(v.z, A, Bc)), mn3, mx3, inv3, sc3);
            vv[j][3] = qact(fmaxf(0.f, fmaf(v.w, A, Bc)), mn3, mx3, inv3, sc3);
        }
#pragma unroll
        for (int xi = 0; xi < 4; ++xi) {
            const int col = xq * 4 + xi + 1;
            const int phys = (oct + col) & 15;
            uint4 pk;
            pk.x = f2bf(vv[0][xi]) | (f2bf(vv[1][xi]) << 16);
            pk.y = f2bf(vv[2][xi]) | (f2bf(vv[3][xi]) << 16);
            pk.z = f2bf(vv[4][xi]) | (f2bf(vv[5][xi]) << 16);
            pk.w = f2bf(vv[6][xi]) | (f2bf(vv[7][xi]) << 16);
            *(uint4*)&lact[((r * 30 + col) * 16 + phys) * 8] = pk;
        }
    }
    __syncthreads();

    const int wv = tid >> 6, lane = tid & 63, r4 = lane & 15, g = lane >> 4;
    int py[4], px[4];
#pragma unroll
    for (int i = 0; i < 4; ++i) {
        const int p = (wv * 4 + i) * 16 + r4;
        py[i] = p / 28; px[i] = p % 28;
    }
    f32x4 acc[2][4];
#pragma unroll
    for (int ct = 0; ct < 2; ++ct)
#pragma unroll
        for (int i = 0; i < 4; ++i) acc[ct][i] = f32x4{0.f, 0.f, 0.f, 0.f};

    const unsigned short* qw2 = (const unsigned short*)(ws + QW2_OFF);
    for (int tap = 0; tap < 9; ++tap) {
        const int dy = tap / 3, dx = tap % 3;
        bf16x8 afr[2][4];
#pragma unroll
        for (int ct = 0; ct < 2; ++ct)
#pragma unroll
            for (int c4 = 0; c4 < 4; ++c4) {
                const int co = ct * 16 + r4;
                afr[ct][c4] = *(const bf16x8*)&qw2[(size_t)co * 1152 + tap * 128 + c4 * 32 + g * 8];
            }
#pragma unroll
        for (int c4 = 0; c4 < 4; ++c4) {
            bf16x8 bfr[4];
#pragma unroll
            for (int i = 0; i < 4; ++i) {
                const int row = py[i] + dy, col = px[i] + dx;
                const int phys = (c4 * 4 + g + col) & 15;
                bfr[i] = *(const bf16x8*)&lact[((row * 30 + col) * 16 + phys) * 8];
            }
#pragma unroll
            for (int ct = 0; ct < 2; ++ct)
#pragma unroll
                for (int i = 0; i < 4; ++i)
                    acc[ct][i] = __builtin_amdgcn_mfma_f32_16x16x32_bf16(afr[ct][c4], bfr[i], acc[ct][i], 0, 0, 0);
        }
    }

#pragma unroll
    for (int ct = 0; ct < 2; ++ct)
#pragma unroll
        for (int i = 0; i < 4; ++i) {
            const int pf = wv * 4 + i;
            if (pf < 7) {
                const int p = pf * 16 + r4;
#pragma unroll
                for (int r = 0; r < 4; ++r) {
                    const int co = ct * 16 + g * 4 + r;
                    out[((size_t)b * C_TOT + 512 + co) * HW + y0 * 28 + p] = acc[ct][i][r];
                }
            }
        }
}

extern "C" void kernel_launch(void* const* d_in, const int* in_sizes, int n_in,
                              void* d_out, int out_size, void* d_ws, size_t ws_size,
                              hipStream_t stream) {
    const float* x       = (const float*)d_in[0];
    const float* bn1_w   = (const float*)d_in[1];
    const float* bn1_b   = (const float*)d_in[2];
    const float* conv1_w = (const float*)d_in[3];
    const float* rbn_w   = (const float*)d_in[4];
    const float* rbn_b   = (const float*)d_in[5];
    const float* conv2_w = (const float*)d_in[6];
    float* out = (float*)d_out;
    float* ws  = (float*)d_ws;   // needs ~27 MB

    k_stats<<<dim3(512, 8), 256, 0, stream>>>(x, ws);
    k_prep_red<<<44, 256, 0, stream>>>(conv1_w, conv2_w, bn1_w, bn1_b, ws);
    k_prep_fin<<<1, 256, 0, stream>>>(rbn_w, rbn_b, ws);
    k_prep_quant<<<40, 256, 0, stream>>>(conv1_w, conv2_w, ws);
    k_conv1<<<dim3(7, 64), 256, 0, stream>>>(x, out, ws);
    k_rbn_combine<<<128, 64, 0, stream>>>(ws);
    k_prep2b<<<1, 64, 0, stream>>>(ws);
    k_conv2<<<dim3(7, 64), 128, 0, stream>>>(out, ws);
}

// Round 7
// 102.238 us; speedup vs baseline: 3.2101x; 1.0379x over previous
//
#include <hip/hip_runtime.h>
#include <math.h>

// Dims: x[64,512,28,28] -> out[64,544,28,28] fp32
static constexpr int BB    = 64;
static constexpr int C_IN  = 512;
static constexpr int C_MID = 128;
static constexpr int C_OUT = 32;
static constexpr int C_TOT = 544;
static constexpr int HW    = 784;   // 28*28

// ---- workspace layout (float offsets). Total ~27 MB ----
static constexpr size_t H2_OFF    = 0;                         // 64*128*784 = 6,422,528
static constexpr size_t QW1_OFF   = 6422528;                   // bf16 [8][128][64] swizzled
static constexpr size_t QW2_OFF   = QW1_OFF + 65536;           // bf16 [co32][k1152]
static constexpr size_t PSTAT_OFF = QW2_OFF + 49152;           // [512][8][4]
static constexpr size_t BNA_OFF   = PSTAT_OFF + 16384;         // 512
static constexpr size_t BNB_OFF   = BNA_OFF + 512;             // 512
static constexpr size_t A2_OFF    = BNB_OFF + 512;             // 128
static constexpr size_t B2_OFF    = A2_OFF + 128;
static constexpr size_t QRW_OFF   = B2_OFF + 128;
static constexpr size_t QRB_OFF   = QRW_OFF + 128;
static constexpr size_t SCAL_OFF  = QRB_OFF + 128;             // 16 scalars
// SCAL: 0=mn1 1=scale1 2=inv1 6=mx1
static constexpr size_t ACELL_OFF = SCAL_OFF + 16;             // 8 uints: [0..2]=mins(w1,w2,h3) [4..6]=maxs
static constexpr size_t RP_OFF    = ACELL_OFF + 112;           // rbn partials [co128][b64][pt7][3]

#define DEVFN __device__ __forceinline__

typedef __bf16 bf16x8 __attribute__((ext_vector_type(8)));
typedef float  f32x4  __attribute__((ext_vector_type(4)));

DEVFN float qact(float v, float mn, float mx, float inv, float sc) {
    v = fminf(fmaxf(v, mn), mx);
    return fmaf(rintf((v - mn) * inv), sc, mn);   // rintf == round-half-even == jnp.round
}

DEVFN unsigned f2bf(float f) {                    // fp32 -> bf16 bits, RNE
    unsigned u = __float_as_uint(f);
    return (u + 0x7fffu + ((u >> 16) & 1u)) >> 16;
}

DEVFN unsigned fkey(float f) {                    // monotone float -> uint key (handles negatives)
    const unsigned u = __float_as_uint(f);
    return (u & 0x80000000u) ? ~u : (u | 0x80000000u);
}
DEVFN float funkey(unsigned k) {
    const unsigned u = (k & 0x80000000u) ? (k & 0x7FFFFFFFu) : ~k;
    return __uint_as_float(u);
}

// ---------- K-1: init atomic cells ----------
__global__ void k_init(float* __restrict__ ws) {
    unsigned* cells = (unsigned*)(ws + ACELL_OFF);
    const int t = threadIdx.x;
    if (t < 3) cells[t] = 0xFFFFFFFFu;             // mins: w1key, w2key, h3bits
    else if (t < 6) cells[4 + (t - 3)] = 0u;       // maxs
}

// ---------- K0: per-channel x stats (4096 blocks) + weight min/max (40 blocks, atomics) ----------
__global__ __launch_bounds__(256) void k_stats(const float* __restrict__ x,
                                               const float* __restrict__ conv1_w,
                                               const float* __restrict__ conv2_w,
                                               float* __restrict__ ws) {
    const int bid = blockIdx.x, tid = threadIdx.x;
    __shared__ float r0[256], r1[256], r2[256], r3[256];

    if (bid < 4096) {                              // x stats: (c, 8-image group)
        const int c = bid >> 3, bg = bid & 7;
        float s = 0.f, s2 = 0.f, mn = INFINITY, mx = -INFINITY;
        if (tid < 224) {
#pragma unroll
            for (int k = 0; k < 7; ++k) {
                const int idx = k * 224 + tid;
                const int b = bg * 8 + idx / 196, j = idx % 196;
                const float4 v = ((const float4*)(x + ((size_t)b * C_IN + c) * HW))[j];
                s  += (v.x + v.y) + (v.z + v.w);
                s2 += v.x * v.x + v.y * v.y + v.z * v.z + v.w * v.w;
                mn = fminf(mn, fminf(fminf(v.x, v.y), fminf(v.z, v.w)));
                mx = fmaxf(mx, fmaxf(fmaxf(v.x, v.y), fmaxf(v.z, v.w)));
            }
        }
        r0[tid] = s; r1[tid] = s2; r2[tid] = mn; r3[tid] = mx;
        __syncthreads();
        for (int off = 128; off > 0; off >>= 1) {
            if (tid < off) {
                r0[tid] += r0[tid + off];
                r1[tid] += r1[tid + off];
                r2[tid] = fminf(r2[tid], r2[tid + off]);
                r3[tid] = fmaxf(r3[tid], r3[tid + off]);
            }
            __syncthreads();
        }
        if (tid == 0) {
            float* p = ws + PSTAT_OFF + ((size_t)c * 8 + bg) * 4;
            p[0] = r0[0]; p[1] = r1[0]; p[2] = r2[0]; p[3] = r3[0];
        }
    } else {                                       // weight min/max partial + atomic
        float mn = INFINITY, mx = -INFINITY;
        if (bid < 4128) {                          // conv1_w: 32 blocks x 2048 floats
            const float4* src = (const float4*)conv1_w + (size_t)(bid - 4096) * 512;
            for (int i = tid; i < 512; i += 256) {
                const float4 v = src[i];
                mn = fminf(mn, fminf(fminf(v.x, v.y), fminf(v.z, v.w)));
                mx = fmaxf(mx, fmaxf(fmaxf(v.x, v.y), fmaxf(v.z, v.w)));
            }
        } else {                                   // conv2_w: 8 blocks x 4608 floats
            const float4* src = (const float4*)conv2_w + (size_t)(bid - 4128) * 1152;
            for (int i = tid; i < 1152; i += 256) {
                const float4 v = src[i];
                mn = fminf(mn, fminf(fminf(v.x, v.y), fminf(v.z, v.w)));
                mx = fmaxf(mx, fmaxf(fmaxf(v.x, v.y), fmaxf(v.z, v.w)));
            }
        }
        r2[tid] = mn; r3[tid] = mx;
        __syncthreads();
        for (int off = 128; off > 0; off >>= 1) {
            if (tid < off) { r2[tid] = fminf(r2[tid], r2[tid + off]); r3[tid] = fmaxf(r3[tid], r3[tid + off]); }
            __syncthreads();
        }
        if (tid == 0) {
            unsigned* cells = (unsigned*)(ws + ACELL_OFF);
            const int w = (bid < 4128) ? 0 : 1;
            atomicMin(&cells[w],     fkey(r2[0]));
            atomicMax(&cells[4 + w], fkey(r3[0]));
        }
    }
}

// ---------- K1: all prep — weight quantize (scales inline from cells), BN affine + h1 range, rbn quantize ----------
__global__ __launch_bounds__(256) void k_prep(const float* __restrict__ conv1_w,
                                              const float* __restrict__ conv2_w,
                                              const float* __restrict__ bn1_w,
                                              const float* __restrict__ bn1_b,
                                              const float* __restrict__ rbn_w,
                                              const float* __restrict__ rbn_b,
                                              float* __restrict__ ws) {
    const int b = blockIdx.x, tid = threadIdx.x;
    const unsigned* cells = (const unsigned*)(ws + ACELL_OFF);
    __shared__ float ra[256], rb[256];
    __shared__ float s_mn, s_sc;

    if (b < 32) {                                  // conv1_w -> bf16 swizzled [ks][co][k64]
        const float mnw = funkey(cells[0]), mxw = funkey(cells[4]);
        const float scw = fmaxf((mxw - mnw) / 255.f, 1e-8f);
        unsigned short* qw = (unsigned short*)(ws + QW1_OFF);
        const int base = b * 2048;
#pragma unroll
        for (int t = 0; t < 8; ++t) {
            const int i = base + t * 256 + tid;
            const int co = i >> 9, k = i & 511;
            const float v = conv1_w[i];
            const float qv = fmaf(rintf((v - mnw) / scw), scw, mnw);
            const int ks = k >> 6, kc = (k >> 3) & 7, klo = k & 7;
            qw[(((size_t)ks * 128 + co) << 6) + (((kc ^ (co & 7)) << 3) | klo)] = (unsigned short)f2bf(qv);
        }
    } else if (b < 40) {                           // conv2_w -> bf16 [co][k = tap*128 + ci]
        const float mnw = funkey(cells[1]), mxw = funkey(cells[5]);
        const float scw = fmaxf((mxw - mnw) / 255.f, 1e-8f);
        unsigned short* qw2 = (unsigned short*)(ws + QW2_OFF);
        const int base = (b - 32) * 4608;
        for (int i2 = tid; i2 < 4608; i2 += 256) {
            const int i = base + i2;
            const int co = i / 1152, r = i % 1152, ci = r / 9, tap = r % 9;
            const float v = conv2_w[i];
            const float qv = fmaf(rintf((v - mnw) / scw), scw, mnw);
            qw2[(size_t)co * 1152 + tap * 128 + ci] = (unsigned short)f2bf(qv);
        }
    } else if (b == 40) {                          // BN affine + global h1 range
        float lmn = INFINITY, lmx = -INFINITY;
        for (int c = tid; c < 512; c += 256) {
            const float* p = ws + PSTAT_OFF + (size_t)c * 32;
            float s = 0.f, s2 = 0.f, cmn = INFINITY, cmx = -INFINITY;
            for (int g = 0; g < 8; ++g) {
                s += p[g * 4 + 0]; s2 += p[g * 4 + 1];
                cmn = fminf(cmn, p[g * 4 + 2]); cmx = fmaxf(cmx, p[g * 4 + 3]);
            }
            const float n = 50176.f;
            const float mean = s / n;
            const float var  = s2 / n - mean * mean;
            const float rstd = rsqrtf(var + 1e-5f);
            const float A  = rstd * bn1_w[c];
            const float Bc = bn1_b[c] - mean * A;
            ws[BNA_OFF + c] = A; ws[BNB_OFF + c] = Bc;
            const float v1 = A * cmn + Bc, v2 = A * cmx + Bc;
            lmn = fminf(lmn, fmaxf(0.f, fminf(v1, v2)));
            lmx = fmaxf(lmx, fmaxf(0.f, fmaxf(v1, v2)));
        }
        ra[tid] = lmn; rb[tid] = lmx;
        __syncthreads();
        for (int off = 128; off > 0; off >>= 1) {
            if (tid < off) { ra[tid] = fminf(ra[tid], ra[tid + off]); rb[tid] = fmaxf(rb[tid], rb[tid + off]); }
            __syncthreads();
        }
        if (tid == 0) {
            const float mn1 = ra[0], mx1 = rb[0];
            const float sc = fmaxf((mx1 - mn1) / 255.f, 1e-8f);
            ws[SCAL_OFF + 0] = mn1; ws[SCAL_OFF + 1] = sc; ws[SCAL_OFF + 2] = 1.f / sc; ws[SCAL_OFF + 6] = mx1;
        }
    } else {                                       // b == 41: rbn_w / rbn_b quantize
        for (int which = 0; which < 2; ++which) {
            const float* src = which ? rbn_b : rbn_w;
            const size_t dst = which ? QRB_OFF : QRW_OFF;
            float v = 0.f;
            ra[tid] = INFINITY; rb[tid] = -INFINITY;
            if (tid < 128) { v = src[tid]; ra[tid] = v; rb[tid] = v; }
            __syncthreads();
            for (int off = 128; off > 0; off >>= 1) {
                if (tid < off) { ra[tid] = fminf(ra[tid], ra[tid + off]); rb[tid] = fmaxf(rb[tid], rb[tid + off]); }
                __syncthreads();
            }
            if (tid == 0) { s_mn = ra[0]; s_sc = fmaxf((rb[0] - ra[0]) / 255.f, 1e-8f); }
            __syncthreads();
            if (tid < 128) ws[dst + tid] = fmaf(rintf((v - s_mn) / s_sc), s_sc, s_mn);
            __syncthreads();
        }
    }
}

// ---------- K2: 1x1 conv MFMA GEMM + fused concat-copy + fused RBN partial stats ----------
__global__ __launch_bounds__(256, 2) void k_conv1(const float* __restrict__ x,
                                                  float* __restrict__ out,
                                                  float* __restrict__ ws) {
    __shared__ __align__(16) unsigned short wt[128 * 64];
    __shared__ __align__(16) unsigned short ht[112 * 64];
    const int tid = threadIdx.x;
    const int pt = blockIdx.x, b = blockIdx.y;
    const int p0 = pt * 112;
    const float mn1 = ws[SCAL_OFF + 0], sc1 = ws[SCAL_OFF + 1];
    const float inv1 = ws[SCAL_OFF + 2], mx1 = ws[SCAL_OFF + 6];
    const unsigned short* qw1 = (const unsigned short*)(ws + QW1_OFF);
    const float* xb = x + (size_t)b * C_IN * HW;
    float* outb = out + (size_t)b * C_TOT * HW;

    const int o = tid & 7, q = tid >> 3;
    const int wv = tid >> 6, g = (tid >> 4) & 3, r4 = tid & 15;

    f32x4 acc[2][7];
#pragma unroll
    for (int i = 0; i < 2; ++i)
#pragma unroll
        for (int j = 0; j < 7; ++j) acc[i][j] = f32x4{0.f, 0.f, 0.f, 0.f};

    for (int ks = 0; ks < 8; ++ks) {
        const float4* wsrc = (const float4*)(qw1 + (size_t)ks * 8192);
        float4* wdst = (float4*)wt;
#pragma unroll
        for (int i = 0; i < 4; ++i) wdst[tid + i * 256] = wsrc[tid + i * 256];

        if (tid < 224) {
            const int ci0 = ks * 64 + o * 8;
            float vv[8][4];
#pragma unroll
            for (int j = 0; j < 8; ++j) {
                const f32x4 v = *(const f32x4*)(xb + (size_t)(ci0 + j) * HW + p0 + q * 4);
                __builtin_nontemporal_store(v, (f32x4*)(outb + (size_t)(ci0 + j) * HW + p0 + q * 4));
                const float A = ws[BNA_OFF + ci0 + j], Bc = ws[BNB_OFF + ci0 + j];
                vv[j][0] = qact(fmaxf(0.f, fmaf(v.x, A, Bc)), mn1, mx1, inv1, sc1);
                vv[j][1] = qact(fmaxf(0.f, fmaf(v.y, A, Bc)), mn1, mx1, inv1, sc1);
                vv[j][2] = qact(fmaxf(0.f, fmaf(v.z, A, Bc)), mn1, mx1, inv1, sc1);
                vv[j][3] = qact(fmaxf(0.f, fmaf(v.w, A, Bc)), mn1, mx1, inv1, sc1);
            }
#pragma unroll
            for (int r = 0; r < 4; ++r) {
                const int p = q * 4 + r;
                uint4 pk;
                pk.x = f2bf(vv[0][r]) | (f2bf(vv[1][r]) << 16);
                pk.y = f2bf(vv[2][r]) | (f2bf(vv[3][r]) << 16);
                pk.z = f2bf(vv[4][r]) | (f2bf(vv[5][r]) << 16);
                pk.w = f2bf(vv[6][r]) | (f2bf(vv[7][r]) << 16);
                *(uint4*)&ht[p * 64 + ((o ^ (p & 7)) << 3)] = pk;
            }
        }
        __syncthreads();

#pragma unroll
        for (int ksub = 0; ksub < 2; ++ksub) {
            const int kk = ksub * 4 + g;
            bf16x8 af[2], bfr[7];
#pragma unroll
            for (int ct = 0; ct < 2; ++ct) {
                const int co = wv * 32 + ct * 16 + r4;
                af[ct] = *(const bf16x8*)&wt[co * 64 + ((kk ^ (co & 7)) << 3)];
            }
#pragma unroll
            for (int pf = 0; pf < 7; ++pf) {
                const int p = pf * 16 + r4;
                bfr[pf] = *(const bf16x8*)&ht[p * 64 + ((kk ^ (p & 7)) << 3)];
            }
#pragma unroll
            for (int ct = 0; ct < 2; ++ct)
#pragma unroll
                for (int pf = 0; pf < 7; ++pf)
                    acc[ct][pf] = __builtin_amdgcn_mfma_f32_16x16x32_bf16(af[ct], bfr[pf], acc[ct][pf], 0, 0, 0);
        }
        __syncthreads();
    }

    float* hb = ws + H2_OFF + (size_t)b * C_MID * HW;
#pragma unroll
    for (int ct = 0; ct < 2; ++ct) {
        const int co0 = wv * 32 + ct * 16 + g * 4;
#pragma unroll
        for (int pf = 0; pf < 7; ++pf) {
            const int p = p0 + pf * 16 + r4;
#pragma unroll
            for (int r = 0; r < 4; ++r)
                hb[(size_t)(co0 + r) * HW + p] = acc[ct][pf][r];
        }
    }

#pragma unroll
    for (int ct = 0; ct < 2; ++ct)
#pragma unroll
        for (int r = 0; r < 4; ++r) {
            float s = 0.f, mn = INFINITY, mx = -INFINITY;
#pragma unroll
            for (int pf = 0; pf < 7; ++pf) {
                const float v = acc[ct][pf][r];
                s += v; mn = fminf(mn, v); mx = fmaxf(mx, v);
            }
#pragma unroll
            for (int m = 1; m < 16; m <<= 1) {
                s  += __shfl_xor(s, m, 64);
                mn  = fminf(mn, __shfl_xor(mn, m, 64));
                mx  = fmaxf(mx, __shfl_xor(mx, m, 64));
            }
            if (r4 == 0) {
                const int co = wv * 32 + ct * 16 + g * 4 + r;
                float* dst = ws + RP_OFF + (((size_t)co * 64 + b) * 7 + pt) * 3;
                dst[0] = s; dst[1] = mn; dst[2] = mx;
            }
        }
}

// ---------- K3: combine RBN partials -> per-channel affine; h3 endpoints via atomics ----------
__global__ __launch_bounds__(64) void k_rbn_combine(float* __restrict__ ws) {
    const int c = blockIdx.x, t = threadIdx.x;
    const int ch = t >> 2, sub = t & 3;            // chunk 0..15, sub-image 0..3
    const int b = ch * 4 + sub;
    const float* rp = ws + RP_OFF + ((size_t)c * 64 + b) * 21;
    float s = 0.f, mn = INFINITY, mx = -INFINITY;
#pragma unroll
    for (int pt = 0; pt < 7; ++pt) {
        s += rp[pt * 3 + 0];
        mn = fminf(mn, rp[pt * 3 + 1]);
        mx = fmaxf(mx, rp[pt * 3 + 2]);
    }
#pragma unroll
    for (int m = 1; m < 4; m <<= 1) {              // reduce 4 images -> chunk
        s  += __shfl_xor(s, m, 64);
        mn  = fminf(mn, __shfl_xor(mn, m, 64));
        mx  = fmaxf(mx, __shfl_xor(mx, m, 64));
    }
    float smx = mx, smn = mn, stot = s, gmn = mn, gmx = mx;
#pragma unroll
    for (int m = 4; m < 64; m <<= 1) {
        smx  += __shfl_xor(smx, m, 64);
        smn  += __shfl_xor(smn, m, 64);
        stot += __shfl_xor(stot, m, 64);
        gmn   = fminf(gmn, __shfl_xor(gmn, m, 64));
        gmx   = fmaxf(gmx, __shfl_xor(gmx, m, 64));
    }
    if (t == 0) {
        const float mm = smx * (1.f / 16.f), mnm = smn * (1.f / 16.f);
        const float mean = stot / 50176.f;
        const double PI_D = 3.14159265358979323846;
        const double sfd = 0.175 * (1.0 + sqrt(PI_D * log(4.0))) / sqrt(2.0 * log(3136.0));
        const float scale = 1.f / ((mm - mnm) * (float)sfd + 1e-5f);
        const float A  = scale * ws[QRW_OFF + c];
        const float Bc = ws[QRB_OFF + c] - mean * A;
        ws[A2_OFF + c] = A; ws[B2_OFF + c] = Bc;
        const float v1 = A * gmn + Bc, v2 = A * gmx + Bc;
        const float lo = fmaxf(0.f, fminf(v1, v2));
        const float hi = fmaxf(0.f, fmaxf(v1, v2));
        unsigned* cells = (unsigned*)(ws + ACELL_OFF);
        atomicMin(&cells[2], __float_as_uint(lo));   // non-negative floats: bit order == value order
        atomicMax(&cells[6], __float_as_uint(hi));
    }
}

// ---------- K4: 3x3 conv via MFMA implicit im2col (h3 scale derived inline) ----------
__global__ __launch_bounds__(128) void k_conv2(float* __restrict__ out, const float* __restrict__ ws) {
    __shared__ __align__(16) unsigned short lact[7 * 30 * 128];
    const int tid = threadIdx.x;
    const int pt = blockIdx.x, b = blockIdx.y;
    const int y0 = pt * 4;
    const unsigned* cells = (const unsigned*)(ws + ACELL_OFF);
    const float mn3 = __uint_as_float(cells[2]);
    const float mx3 = __uint_as_float(cells[6]);
    const float sc3 = fmaxf((mx3 - mn3) / 255.f, 1e-8f);
    const float inv3 = 1.f / sc3;

    {
        const uint4 z = {0u, 0u, 0u, 0u};
        uint4* lp = (uint4*)lact;
        for (int i = tid; i < 3360; i += 128) lp[i] = z;
    }
    __syncthreads();

    const float* h2b = ws + H2_OFF + (size_t)b * C_MID * HW;
    for (int task = tid; task < 672; task += 128) {
        const int oct = task / 42, rem = task % 42, r = rem / 7, xq = rem % 7;
        const int gy = y0 - 1 + r;
        if (gy < 0 || gy > 27) continue;
        float vv[8][4];
#pragma unroll
        for (int j = 0; j < 8; ++j) {
            const int ci = oct * 8 + j;
            const float4 v = *(const float4*)(h2b + (size_t)ci * HW + gy * 28 + xq * 4);
            const float A = ws[A2_OFF + ci], Bc = ws[B2_OFF + ci];
            vv[j][0] = qact(fmaxf(0.f, fmaf(v.x, A, Bc)), mn3, mx3, inv3, sc3);
            vv[j][1] = qact(fmaxf(0.f, fmaf(v.y, A, Bc)), mn3, mx3, inv3, sc3);
            vv[j][2] = qact(fmaxf(0.f, fmaf(v.z, A, Bc)), mn3, mx3, inv3, sc3);
            vv[j][3] = qact(fmaxf(0.f, fmaf(v.w, A, Bc)), mn3, mx3, inv3, sc3);
        }
#pragma unroll
        for (int xi = 0; xi < 4; ++xi) {
            const int col = xq * 4 + xi + 1;
            const int phys = (oct + col) & 15;
            uint4 pk;
            pk.x = f2bf(vv[0][xi]) | (f2bf(vv[1][xi]) << 16);
            pk.y = f2bf(vv[2][xi]) | (f2bf(vv[3][xi]) << 16);
            pk.z = f2bf(vv[4][xi]) | (f2bf(vv[5][xi]) << 16);
            pk.w = f2bf(vv[6][xi]) | (f2bf(vv[7][xi]) << 16);
            *(uint4*)&lact[((r * 30 + col) * 16 + phys) * 8] = pk;
        }
    }
    __syncthreads();

    const int wv = tid >> 6, lane = tid & 63, r4 = lane & 15, g = lane >> 4;
    int py[4], px[4];
#pragma unroll
    for (int i = 0; i < 4; ++i) {
        const int p = (wv * 4 + i) * 16 + r4;
        py[i] = p / 28; px[i] = p % 28;
    }
    f32x4 acc[2][4];
#pragma unroll
    for (int ct = 0; ct < 2; ++ct)
#pragma unroll
        for (int i = 0; i < 4; ++i) acc[ct][i] = f32x4{0.f, 0.f, 0.f, 0.f};

    const unsigned short* qw2 = (const unsigned short*)(ws + QW2_OFF);
    for (int tap = 0; tap < 9; ++tap) {
        const int dy = tap / 3, dx = tap % 3;
        bf16x8 afr[2][4];
#pragma unroll
        for (int ct = 0; ct < 2; ++ct)
#pragma unroll
            for (int c4 = 0; c4 < 4; ++c4) {
                const int co = ct * 16 + r4;
                afr[ct][c4] = *(const bf16x8*)&qw2[(size_t)co * 1152 + tap * 128 + c4 * 32 + g * 8];
            }
#pragma unroll
        for (int c4 = 0; c4 < 4; ++c4) {
            bf16x8 bfr[4];
#pragma unroll
            for (int i = 0; i < 4; ++i) {
                const int row = py[i] + dy, col = px[i] + dx;
                const int phys = (c4 * 4 + g + col) & 15;
                bfr[i] = *(const bf16x8*)&lact[((row * 30 + col) * 16 + phys) * 8];
            }
#pragma unroll
            for (int ct = 0; ct < 2; ++ct)
#pragma unroll
                for (int i = 0; i < 4; ++i)
                    acc[ct][i] = __builtin_amdgcn_mfma_f32_16x16x32_bf16(afr[ct][c4], bfr[i], acc[ct][i], 0, 0, 0);
        }
    }

#pragma unroll
    for (int ct = 0; ct < 2; ++ct)
#pragma unroll
        for (int i = 0; i < 4; ++i) {
            const int pf = wv * 4 + i;
            if (pf < 7) {
                const int p = pf * 16 + r4;
#pragma unroll
                for (int r = 0; r < 4; ++r) {
                    const int co = ct * 16 + g * 4 + r;
                    out[((size_t)b * C_TOT + 512 + co) * HW + y0 * 28 + p] = acc[ct][i][r];
                }
            }
        }
}

extern "C" void kernel_launch(void* const* d_in, const int* in_sizes, int n_in,
                              void* d_out, int out_size, void* d_ws, size_t ws_size,
                              hipStream_t stream) {
    const float* x       = (const float*)d_in[0];
    const float* bn1_w   = (const float*)d_in[1];
    const float* bn1_b   = (const float*)d_in[2];
    const float* conv1_w = (const float*)d_in[3];
    const float* rbn_w   = (const float*)d_in[4];
    const float* rbn_b   = (const float*)d_in[5];
    const float* conv2_w = (const float*)d_in[6];
    float* out = (float*)d_out;
    float* ws  = (float*)d_ws;   // needs ~27 MB

    k_init<<<1, 64, 0, stream>>>(ws);
    k_stats<<<4136, 256, 0, stream>>>(x, conv1_w, conv2_w, ws);
    k_prep<<<42, 256, 0, stream>>>(conv1_w, conv2_w, bn1_w, bn1_b, rbn_w, rbn_b, ws);
    k_conv1<<<dim3(7, 64), 256, 0, stream>>>(x, out, ws);
    k_rbn_combine<<<128, 64, 0, stream>>>(ws);
    k_conv2<<<dim3(7, 64), 128, 0, stream>>>(out, ws);
}